// Round 2
// baseline (756.154 us; speedup 1.0000x reference)
//
#include <hip/hip_runtime.h>
#include <hip/hip_bf16.h>

// TransformerBlock on MI355X (gfx950) — round 6: counted-vmcnt GEMM pipeline.
// All GEMMs move to a 256x256-tile, BK=64, 8-wave (512-thr) double-buffered
// schedule with raw s_barrier + s_waitcnt vmcnt(8) (prefetch loads stay in
// flight across barriers; never drained to 0 in the main loop) + setprio(1)
// around MFMA clusters. This attacks the measured m97-structure ceiling
// (ffn_gemm 158us @ MfmaUtil 39% — schedule-bound, not memory/compute-bound).
// FFN1 un-fused into U-GEMM (writes silu(u)) + V3-GEMM (in-place mul) since
// dual accumulators don't fit the 128x64 per-wave tile. Attn unchanged (R5).
// B=4 S=2048 D=1024 H=16 DK=64 DFF=4096. fp32 in/out, bf16 tensor-core compute.

typedef unsigned short u16;
typedef __attribute__((ext_vector_type(8))) short short8;    // 8 bf16 (MFMA A/B frag)
typedef __attribute__((ext_vector_type(4))) float f32x4;     // 16x16 C/D frag
typedef __attribute__((ext_vector_type(16))) float f32x16;   // 32x32 C/D frag

#define MFMA16(a, b, c) __builtin_amdgcn_mfma_f32_16x16x32_bf16(a, b, c, 0, 0, 0)
#define MFMA32(a, b, c) __builtin_amdgcn_mfma_f32_32x32x16_bf16(a, b, c, 0, 0, 0)

__device__ __forceinline__ u16 f2b(float f) {
  union { float f; unsigned u; } x; x.f = f;
  unsigned r = x.u + 0x7FFFu + ((x.u >> 16) & 1u);   // RNE
  return (u16)(r >> 16);
}
__device__ __forceinline__ float b2f(u16 h) {
  union { unsigned u; float f; } x; x.u = ((unsigned)h) << 16;
  return x.f;
}
__device__ __forceinline__ unsigned pkbf(float a, float b) {
  __hip_bfloat162 h = __float22bfloat162_rn(make_float2(a, b));
  union { __hip_bfloat162 h; unsigned u; } cv; cv.h = h;
  return cv.u;
}
// async global->LDS, 16B per lane; LDS dest = wave-uniform base + lane*16.
__device__ __forceinline__ void async16(const void* g, void* l) {
  __builtin_amdgcn_global_load_lds(
      (const __attribute__((address_space(1))) void*)g,
      (__attribute__((address_space(3))) void*)l, 16, 0, 0);
}

// ---------------------------------------------------------------------------
// GEMM pipeline (bt-form): C[m,n] = sum_k A[m,k]*B[n,k].
// 256x256 block tile, BK=64, 8 waves (2M x 4N), per-wave 128x64 output.
// LDS 128KB (2 dbuf x (A 32KB + B 32KB)), 1 block/CU.
// Schedule per K-tile t:
//   issue stage(tile t+1 -> other buf)   [8 global_load_lds, 16B/lane]
//   s_waitcnt vmcnt(8)                   [tile t's loads landed; t+1 in flight]
//   s_barrier                            [RAW: whole block sees tile t]
//   4 ksteps x {6 ds_read_b128 ; setprio(1) 8 MFMA32 setprio(0)}
//   s_waitcnt lgkmcnt(0); s_barrier      [WAR: reads retired before next stage]
// MODE: 0 = bf16 store; 1 = fp32 store + residual R; 2 = store silu(acc) bf16;
//       3 = in-place Cb *= acc (thread-exclusive elements -> safe in-place).
// ---------------------------------------------------------------------------
template <int MODE>
__global__ __launch_bounds__(512, 1) void gemm5(
    const u16* __restrict__ A, const u16* __restrict__ B,
    u16* __restrict__ Cb, float* __restrict__ Cf, const float* __restrict__ R,
    int M, int N, int K) {
  __shared__ __align__(16) u16 As[2][256 * 64];
  __shared__ __align__(16) u16 Bs[2][256 * 64];
  const int tid = threadIdx.x;
  const int l = tid & 63, w = tid >> 6;
  const int wm = w >> 2, wn = w & 3;
  const int lr = l & 31, lh = l >> 5;
  const size_t m0 = (size_t)blockIdx.y * 256, n0 = (size_t)blockIdx.x * 256;
  f32x16 acc[4][2] = {};

#define STAGE_TILE(buf, kt)                                                  \
  {                                                                          \
    const size_t kofs = (size_t)(kt) * 64;                                   \
    _Pragma("unroll") for (int tt = 0; tt < 4; ++tt) {                       \
      int p = tt * 512 + tid;                                                \
      int r = p >> 3;                                                        \
      int gc = ((p & 7) ^ (r & 7)) << 3;                                     \
      async16(A + (m0 + r) * (size_t)K + kofs + gc, &As[buf][p * 8]);        \
      async16(B + (n0 + r) * (size_t)K + kofs + gc, &Bs[buf][p * 8]);        \
    }                                                                        \
  }

  const int NT = K >> 6;
  STAGE_TILE(0, 0);
  for (int t = 0; t < NT; ++t) {
    const int cur = t & 1;
    if (t + 1 < NT) {
      STAGE_TILE(cur ^ 1, t + 1);
      asm volatile("s_waitcnt vmcnt(8)" ::: "memory");
    } else {
      asm volatile("s_waitcnt vmcnt(0)" ::: "memory");
    }
    __builtin_amdgcn_sched_barrier(0);
    __builtin_amdgcn_s_barrier();
#pragma unroll
    for (int c = 0; c < 4; ++c) {
      const int c8 = c * 2 + lh;
      short8 af[4], bf2[2];
#pragma unroll
      for (int mi = 0; mi < 4; ++mi) {
        int r = wm * 128 + mi * 32 + lr;
        af[mi] = *(const short8*)&As[cur][r * 64 + ((c8 ^ (r & 7)) << 3)];
      }
#pragma unroll
      for (int ni = 0; ni < 2; ++ni) {
        int r = wn * 64 + ni * 32 + lr;
        bf2[ni] = *(const short8*)&Bs[cur][r * 64 + ((c8 ^ (r & 7)) << 3)];
      }
      __builtin_amdgcn_s_setprio(1);
#pragma unroll
      for (int mi = 0; mi < 4; ++mi)
#pragma unroll
        for (int ni = 0; ni < 2; ++ni)
          acc[mi][ni] = MFMA32(af[mi], bf2[ni], acc[mi][ni]);
      __builtin_amdgcn_s_setprio(0);
    }
    asm volatile("s_waitcnt lgkmcnt(0)" ::: "memory");
    __builtin_amdgcn_sched_barrier(0);
    __builtin_amdgcn_s_barrier();
  }
#undef STAGE_TILE

#pragma unroll
  for (int mi = 0; mi < 4; ++mi)
#pragma unroll
    for (int ni = 0; ni < 2; ++ni) {
      size_t n = n0 + wn * 64 + ni * 32 + lr;
#pragma unroll
      for (int reg = 0; reg < 16; ++reg) {
        size_t m = m0 + wm * 128 + mi * 32 + (reg & 3) + 8 * (reg >> 2) + 4 * lh;
        float v = acc[mi][ni][reg];
        if (MODE == 0) {
          Cb[m * (size_t)N + n] = f2b(v);
        } else if (MODE == 1) {
          Cf[m * (size_t)N + n] = v + R[m * (size_t)N + n];
        } else if (MODE == 2) {
          Cb[m * (size_t)N + n] = f2b(v / (1.0f + __expf(-v)));   // silu, fp32
        } else {  // MODE 3: H = G * acc, in-place over G
          float g = b2f(Cb[m * (size_t)N + n]);
          Cb[m * (size_t)N + n] = f2b(v * g);
        }
      }
    }
}

// ---------------------------------------------------------------------------
// Flash attention v5 (causal), S^T formulation, q-tile 128, fused q-subtiles.
// Unchanged from round 5 (passed; both q-subtiles share each K/V LDS read).
// ---------------------------------------------------------------------------
__global__ __launch_bounds__(256, 2) void attn_k(
    const u16* __restrict__ qh, const u16* __restrict__ kh,
    const u16* __restrict__ vt, u16* __restrict__ aout) {
  __shared__ __align__(16) u16 Ks[128 * 64];
  __shared__ __align__(16) u16 Vs[64 * 128];
  __shared__ __align__(16) u16 Ps[128 * 136];
  const int tid = threadIdx.x;
  const int l = tid & 63, w = tid >> 6;
  const int q = l & 15, lq = l >> 4;
  const int q0 = (int)(gridDim.x - 1 - blockIdx.x) * 128;  // heavy blocks first
  const int bh = blockIdx.y;
  const size_t base = (size_t)bh * (2048 * 64);
  const int nt = (q0 >> 7) + 1;

  int qcol[2] = {q0 + w * 16 + q, q0 + 64 + w * 16 + q};
  short8 bq[2][2];
#pragma unroll
  for (int sub = 0; sub < 2; ++sub)
#pragma unroll
    for (int kk = 0; kk < 2; ++kk)
      bq[sub][kk] = *(const short8*)(qh + base + (size_t)qcol[sub] * 64 + kk * 32 + lq * 8);

  f32x4 o[2][4] = {};
  float mI[2] = {-1e30f, -1e30f}, lI[2] = {0.0f, 0.0f};
  u16* pr0 = &Ps[(w * 16 + q) * 136];
  u16* pr1 = &Ps[(64 + w * 16 + q) * 136];

  for (int it = 0; it < nt; ++it) {
    const int kv0 = it << 7;
    if (it) __syncthreads();  // WAR: all waves done with previous tile
#pragma unroll
    for (int t = 0; t < 4; ++t) {
      int p = t * 256 + tid;
      int r = p >> 3, cs = p & 7;
      async16(kh + base + (size_t)(kv0 + r) * 64 + ((cs ^ (r & 7)) << 3), &Ks[p * 8]);
    }
#pragma unroll
    for (int t = 0; t < 4; ++t) {
      int p = t * 256 + tid;
      int r = p >> 4, cs = p & 15;
      async16(vt + base + (size_t)r * 2048 + kv0 + ((cs ^ (r & 15)) << 3), &Vs[p * 8]);
    }
    __syncthreads();
    const bool last = (it == nt - 1);

    // S^T = K · Q^T for BOTH subtiles: one ak read feeds two MFMAs.
    f32x4 s[2][8] = {};
#pragma unroll
    for (int kk = 0; kk < 2; ++kk) {
#pragma unroll
      for (int mt = 0; mt < 8; ++mt) {
        int row = mt * 16 + q;
        short8 ak = *(const short8*)&Ks[row * 64 + (((kk * 4 + lq) ^ (q & 7)) << 3)];
        s[0][mt] = MFMA16(ak, bq[0][kk], s[0][mt]);
        s[1][mt] = MFMA16(ak, bq[1][kk], s[1][mt]);
      }
    }
    if (last) {  // causal mask
#pragma unroll
      for (int sub = 0; sub < 2; ++sub)
#pragma unroll
        for (int mt = 0; mt < 8; ++mt)
#pragma unroll
          for (int r = 0; r < 4; ++r)
            if (kv0 + mt * 16 + lq * 4 + r > qcol[sub]) s[sub][mt][r] = -1e30f;
    }
    // online softmax per subtile, exp2 domain (Q prescaled in rope_k)
#pragma unroll
    for (int sub = 0; sub < 2; ++sub) {
      float mx = -1e30f;
#pragma unroll
      for (int mt = 0; mt < 8; ++mt)
#pragma unroll
        for (int r = 0; r < 4; ++r) mx = fmaxf(mx, s[sub][mt][r]);
      mx = fmaxf(mx, __shfl_xor(mx, 16, 64));
      mx = fmaxf(mx, __shfl_xor(mx, 32, 64));
      const float mn = fmaxf(mI[sub], mx);
      const float al = exp2f(mI[sub] - mn);
      mI[sub] = mn;
      float rs = 0.0f;
#pragma unroll
      for (int mt = 0; mt < 8; ++mt)
#pragma unroll
        for (int r = 0; r < 4; ++r) {
          float p = exp2f(s[sub][mt][r] - mn);
          s[sub][mt][r] = p;
          rs += p;
        }
      rs += __shfl_xor(rs, 16, 64);
      rs += __shfl_xor(rs, 32, 64);
      lI[sub] = lI[sub] * al + rs;
#pragma unroll
      for (int mt = 0; mt < 4; ++mt)
#pragma unroll
        for (int r = 0; r < 4; ++r) o[sub][mt][r] *= al;
      u16* pr = sub ? pr1 : pr0;
#pragma unroll
      for (int mt = 0; mt < 8; ++mt) {
        uint2 pd;
        pd.x = pkbf(s[sub][mt][0], s[sub][mt][1]);
        pd.y = pkbf(s[sub][mt][2], s[sub][mt][3]);
        *(uint2*)&pr[mt * 16 + lq * 4] = pd;
      }
    }
    // O^T += V^T · P^T for BOTH subtiles: one av read feeds two MFMAs.
#pragma unroll
    for (int kk = 0; kk < 4; ++kk) {
      short8 bp0 = *(const short8*)&pr0[kk * 32 + lq * 8];
      short8 bp1 = *(const short8*)&pr1[kk * 32 + lq * 8];
#pragma unroll
      for (int mt = 0; mt < 4; ++mt) {
        int row = mt * 16 + q;
        short8 av = *(const short8*)&Vs[row * 128 + (((kk * 4 + lq) ^ (row & 15)) << 3)];
        o[0][mt] = MFMA16(av, bp0, o[0][mt]);
        o[1][mt] = MFMA16(av, bp1, o[1][mt]);
      }
    }
  }
  const int b = bh >> 4, h = bh & 15;
#pragma unroll
  for (int sub = 0; sub < 2; ++sub) {
    const float inv = 1.0f / lI[sub];
#pragma unroll
    for (int mt = 0; mt < 4; ++mt) {
      uint2 pd;
      pd.x = pkbf(o[sub][mt][0] * inv, o[sub][mt][1] * inv);
      pd.y = pkbf(o[sub][mt][2] * inv, o[sub][mt][3] * inv);
      *(uint2*)&aout[((size_t)(b * 2048 + qcol[sub])) * 1024 + h * 64 + mt * 16 + lq * 4] = pd;
    }
  }
}

// ---------------------------------------------------------------------------
// Elementwise helpers (unchanged)
// ---------------------------------------------------------------------------
__global__ __launch_bounds__(256) void rmsnorm_k(
    const float* __restrict__ x, const float* __restrict__ w, u16* __restrict__ out) {
  const int row = blockIdx.x;
  const int tid = threadIdx.x;
  const float4 v = ((const float4*)(x + (size_t)row * 1024))[tid];
  float ss = v.x * v.x + v.y * v.y + v.z * v.z + v.w * v.w;
#pragma unroll
  for (int d = 1; d < 64; d <<= 1) ss += __shfl_xor(ss, d, 64);
  __shared__ float red[4];
  if ((tid & 63) == 0) red[tid >> 6] = ss;
  __syncthreads();
  const float sc = rsqrtf((red[0] + red[1] + red[2] + red[3]) * (1.0f / 1024.0f) + 1e-5f);
  const float4 wv = ((const float4*)w)[tid];
  u16* o = out + (size_t)row * 1024 + tid * 4;
  o[0] = f2b(v.x * sc * wv.x);
  o[1] = f2b(v.y * sc * wv.y);
  o[2] = f2b(v.z * sc * wv.z);
  o[3] = f2b(v.w * sc * wv.w);
}

// RoPE for q AND k from fused QKV [8192][3072] -> QH/KH [b][h][s][64].
__global__ __launch_bounds__(256) void rope_k(
    const u16* __restrict__ qkv, u16* __restrict__ qh, u16* __restrict__ kh,
    const int* __restrict__ pos) {
  int idx = blockIdx.x * 256 + threadIdx.x;  // 8192 rows * 256 groups
  int grp = idx & 255;
  int row = idx >> 8;
  int which = grp >> 7;  // 0=q, 1=k
  int p = grp & 127;
  int s = row & 2047, b = row >> 11;
  int h = p >> 3, gi = p & 7;
  const u16* src = qkv + (size_t)row * 3072 + which * 1024 + h * 64 + gi * 8;
  uint4 in = *(const uint4*)src;
  const u16* e = (const u16*)&in;
  const float fp = (float)pos[s];
  const float scale = which ? 1.0f : 0.18033688011112042f;  // 0.125*log2(e)
  uint4 outv;
  unsigned* ov = (unsigned*)&outv;
#pragma unroll
  for (int j = 0; j < 4; ++j) {
    int i = gi * 4 + j;  // pair index 0..31
    float xe = b2f(e[2 * j]), xo = b2f(e[2 * j + 1]);
    float inv = exp2f(-(float)(2 * i) * (13.287712379549449f / 64.0f));
    float ang = fp * inv;
    float sn, cs;
    __sincosf(ang, &sn, &cs);
    ov[j] = pkbf((xe * cs - xo * sn) * scale, (xe * sn + xo * cs) * scale);
  }
  u16* dst = (which ? kh : qh) + (((size_t)(b * 16 + h)) * 2048 + s) * 64 + gi * 8;
  *(uint4*)dst = outv;
}

// v (cols 2048..3071 of QKV) -> vT [b][h][d][s], 64x64 LDS tile transpose
__global__ __launch_bounds__(256) void transv_k(
    const u16* __restrict__ qkv, u16* __restrict__ vt) {
  __shared__ u16 t[64][65];
  const int bh = blockIdx.y, s0 = blockIdx.x * 64;
  const int b = bh >> 4, h = bh & 15;
  const int tid = threadIdx.x;
#pragma unroll
  for (int i = 0; i < 16; ++i) {
    int e = i * 256 + tid;
    int sl = e >> 6, d = e & 63;
    t[sl][d] = qkv[((size_t)(b * 2048 + s0 + sl)) * 3072 + 2048 + h * 64 + d];
  }
  __syncthreads();
#pragma unroll
  for (int i = 0; i < 16; ++i) {
    int e = i * 256 + tid;
    int d = e >> 6, sl = e & 63;
    vt[((size_t)(bh * 64 + d)) * 2048 + s0 + sl] = t[sl][d];
  }
}

// All 7 weight tensors fp32->bf16 in one launch.
__global__ __launch_bounds__(256) void cvt_all(
    const float* __restrict__ qp, const float* __restrict__ kp,
    const float* __restrict__ vp, const float* __restrict__ op,
    const float* __restrict__ w1, const float* __restrict__ w3,
    const float* __restrict__ w2,
    u16* __restrict__ WQKV, u16* __restrict__ WO,
    u16* __restrict__ W1, u16* __restrict__ W3, u16* __restrict__ W2) {
  int i = blockIdx.x * 256 + threadIdx.x;  // [0, 4194304)
  const float* src;
  u16* dst;
  int off;
  if (i < 1048576) {
    int seg = i >> 18, within = i & 262143;
    src = (seg == 0) ? qp : (seg == 1) ? kp : (seg == 2) ? vp : op;
    dst = (seg == 3) ? WO : WQKV + (size_t)seg * 1048576;
    off = within;
  } else {
    int j = i - 1048576;
    int seg = j >> 20;
    off = j & 1048575;
    src = (seg == 0) ? w1 : (seg == 1) ? w3 : w2;
    dst = (seg == 0) ? W1 : (seg == 1) ? W3 : W2;
  }
  float4 v = ((const float4*)src)[off];
  u16* o = dst + (size_t)off * 4;
  o[0] = f2b(v.x); o[1] = f2b(v.y); o[2] = f2b(v.z); o[3] = f2b(v.w);
}

// ---------------------------------------------------------------------------
extern "C" void kernel_launch(void* const* d_in, const int* in_sizes, int n_in,
                              void* d_out, int out_size, void* d_ws, size_t ws_size,
                              hipStream_t stream) {
  const float* x   = (const float*)d_in[0];
  const int*   pos = (const int*)d_in[1];
  const float* qp  = (const float*)d_in[2];
  const float* kp  = (const float*)d_in[3];
  const float* vp  = (const float*)d_in[4];
  const float* op  = (const float*)d_in[5];
  const float* w1  = (const float*)d_in[6];
  const float* w2  = (const float*)d_in[7];   // dict order: w2 before w3
  const float* w3  = (const float*)d_in[8];
  const float* ln1 = (const float*)d_in[9];
  const float* ln2 = (const float*)d_in[10];
  float* out = (float*)d_out;
  char* ws = (char*)d_ws;
  const size_t MB = 1024 * 1024;

  u16* WQKV = (u16*)(ws + 0 * MB);    // [3072][1024] stacked q,k,v  (6 MB)
  u16* WO   = (u16*)(ws + 6 * MB);    // 2 MB
  u16* W1   = (u16*)(ws + 8 * MB);    // 8 MB
  u16* W3   = (u16*)(ws + 16 * MB);   // 8 MB
  u16* W2   = (u16*)(ws + 24 * MB);   // 8 MB
  u16* XLN  = (u16*)(ws + 32 * MB);   // 16 MB (dead after QKV gemm)
  u16* QKV  = (u16*)(ws + 48 * MB);   // [8192][3072] 48 MB (48..96)
  u16* QH   = (u16*)(ws + 96 * MB);   // 16 MB
  u16* KH   = (u16*)(ws + 112 * MB);  // 16 MB
  u16* VT   = (u16*)(ws + 128 * MB);  // 16 MB (high-water 144 MB)
  u16* ATT  = (u16*)(ws + 48 * MB);   // reuses QKV (dead after rope/transv)
  u16* XLN2 = (u16*)(ws + 32 * MB);   // reuses dead XLN
  u16* GH   = (u16*)(ws + 48 * MB);   // 64 MB (48..112) over dead ATT/QKV/QH
  (void)in_sizes; (void)n_in; (void)out_size; (void)ws_size;

  cvt_all<<<16384, 256, 0, stream>>>(qp, kp, vp, op, w1, w3, w2,
                                     WQKV, WO, W1, W3, W2);
  rmsnorm_k<<<8192, 256, 0, stream>>>(x, ln1, XLN);
  gemm5<0><<<dim3(12, 32), 512, 0, stream>>>(XLN, WQKV, QKV, nullptr, nullptr, 8192, 3072, 1024);
  rope_k<<<8192, 256, 0, stream>>>(QKV, QH, KH, pos);
  transv_k<<<dim3(32, 64), 256, 0, stream>>>(QKV, VT);
  attn_k<<<dim3(16, 64), 256, 0, stream>>>(QH, KH, VT, ATT);
  gemm5<1><<<dim3(4, 32), 512, 0, stream>>>(ATT, WO, nullptr, out, x, 8192, 1024, 1024);
  rmsnorm_k<<<8192, 256, 0, stream>>>(out, ln2, XLN2);
  // FFN: U = silu(XLN2 @ W1^T) -> GH ; GH *= XLN2 @ W3^T ; out += GH @ W2^T
  gemm5<2><<<dim3(16, 32), 512, 0, stream>>>(XLN2, W1, GH, nullptr, nullptr, 8192, 4096, 1024);
  gemm5<3><<<dim3(16, 32), 512, 0, stream>>>(XLN2, W3, GH, nullptr, nullptr, 8192, 4096, 1024);
  gemm5<1><<<dim3(4, 32), 512, 0, stream>>>(GH, W2, nullptr, out, out, 8192, 1024, 4096);
}

// Round 3
// 739.204 us; speedup vs baseline: 1.0229x; 1.0229x over previous
//
#include <hip/hip_runtime.h>
#include <hip/hip_bf16.h>

// TransformerBlock on MI355X (gfx950) — round 7: true phase-interleaved GEMM.
// R6's coarse 2-phase 256² pipeline measured ~500-680 TF (matches guide's
// m196/m230: coarse split w/o per-phase interleave HURTS). gemm8 is the
// m201-style schedule: 4 quadrant-phases/K-tile, fragments persist in regs
// across phases (24 ds_read_b128/wave/tile, not 48), one half-tile staged
// per phase, counted vmcnt (never 0 in steady state; 2-3 halves always in
// flight across barriers), setprio around MFMA clusters, 2 barriers/phase.
// BM=128 (MIC=1) for N=1024 GEMMs -> 256 even blocks; BM=256 for U/V3.
// Attn + elementwise unchanged (R5/R6, proven). fp32 in/out, bf16 MFMA.

typedef unsigned short u16;
typedef __attribute__((ext_vector_type(8))) short short8;    // 8 bf16 (MFMA A/B frag)
typedef __attribute__((ext_vector_type(4))) float f32x4;     // 16x16 C/D frag
typedef __attribute__((ext_vector_type(16))) float f32x16;   // 32x32 C/D frag

#define MFMA16(a, b, c) __builtin_amdgcn_mfma_f32_16x16x32_bf16(a, b, c, 0, 0, 0)
#define MFMA32(a, b, c) __builtin_amdgcn_mfma_f32_32x32x16_bf16(a, b, c, 0, 0, 0)
#define VMC(N) asm volatile("s_waitcnt vmcnt(" #N ")" ::: "memory")

__device__ __forceinline__ u16 f2b(float f) {
  union { float f; unsigned u; } x; x.f = f;
  unsigned r = x.u + 0x7FFFu + ((x.u >> 16) & 1u);   // RNE
  return (u16)(r >> 16);
}
__device__ __forceinline__ float b2f(u16 h) {
  union { unsigned u; float f; } x; x.u = ((unsigned)h) << 16;
  return x.f;
}
__device__ __forceinline__ unsigned pkbf(float a, float b) {
  __hip_bfloat162 h = __float22bfloat162_rn(make_float2(a, b));
  union { __hip_bfloat162 h; unsigned u; } cv; cv.h = h;
  return cv.u;
}
// async global->LDS, 16B per lane; LDS dest = wave-uniform base + lane*16.
__device__ __forceinline__ void async16(const void* g, void* l) {
  __builtin_amdgcn_global_load_lds(
      (const __attribute__((address_space(1))) void*)g,
      (__attribute__((address_space(3))) void*)l, 16, 0, 0);
}

// ---------------------------------------------------------------------------
// gemm8 (bt-form): C[m,n] = sum_k A[m,k]*B[n,k].
// Tile: BM = MIC*128 rows x BN = 256 cols, BK = 64. 8 waves (2M x 4N).
// LDS: A 2dbuf x 2half x (MIC*64 x 64); B 2dbuf x 2half x (128 x 64).
// Per K-tile, 4 phases (C-quadrants mh,nh). Register-persistent fragments:
//   p1: read A(h0) [MIC*4] + B(h0) [4]; stage A0(t+1); MFMA q(0,0)
//   p2: read B(h1) [4];                 stage B0(t+1); MFMA q(0,1)
//   p3: read A(h1) [MIC*4];             stage B1(t+1); MFMA q(1,0)
//   p4: (no reads);                     stage A1(t+1); MFMA q(1,1)
// vmcnt ledger (LA=MIC, LB=2 loads per half-tile per thread):
//   p1-end vmcnt(2*LA)  -> B1(t) landed (needed p2)
//   p2-end vmcnt(LA+LB) -> A1(t) landed (needed p3)
//   p4-end vmcnt(LA+LB) -> A0,B0(t+1) landed (needed next p1)
// Never 0 in steady state; 2-3 half-tiles stay in flight across barriers.
// MODE: 0 bf16 store; 1 fp32 store + residual; 2 silu(acc) bf16; 3 in-place mul.
// ---------------------------------------------------------------------------
template <int MODE, int MIC>
__global__ __launch_bounds__(512, 2) void gemm8(
    const u16* __restrict__ A, const u16* __restrict__ B,
    u16* __restrict__ Cb, float* __restrict__ Cf, const float* __restrict__ R,
    int M, int N, int K) {
  __shared__ __align__(16) u16 As[2][2][MIC * 64 * 64];
  __shared__ __align__(16) u16 Bs[2][2][128 * 64];
  const int tid = threadIdx.x;
  const int l = tid & 63, w = tid >> 6;
  const int wm = w >> 2, wn = w & 3;   // 2 x 4 wave grid
  const int lr = l & 31, lh = l >> 5;
  const size_t m0 = (size_t)blockIdx.y * (MIC * 128), n0 = (size_t)blockIdx.x * 256;
  f32x16 acc[2][2][MIC] = {};   // [mh][nh][mi]

#define STAGE_A(dd, hh, kt)                                                   \
  { const size_t kofs = (size_t)(kt) * 64;                                    \
    _Pragma("unroll") for (int j = 0; j < MIC; ++j) {                         \
      int p = j * 512 + tid;                                                  \
      int r = p >> 3, c8 = p & 7;                                             \
      async16(A + (m0 + (hh) * (MIC * 64) + r) * (size_t)K + kofs             \
                  + ((c8 ^ (r & 7)) << 3),                                    \
              &As[dd][hh][p * 8]); } }
#define STAGE_B(dd, hh, kt)                                                   \
  { const size_t kofs = (size_t)(kt) * 64;                                    \
    _Pragma("unroll") for (int j = 0; j < 2; ++j) {                           \
      int p = j * 512 + tid;                                                  \
      int r = p >> 3, c8 = p & 7;                                             \
      async16(B + (n0 + (hh) * 128 + r) * (size_t)K + kofs                    \
                  + ((c8 ^ (r & 7)) << 3),                                    \
              &Bs[dd][hh][p * 8]); } }
#define RD_A(MH)                                                              \
  _Pragma("unroll") for (int c = 0; c < 4; ++c) {                             \
    const int c8 = c * 2 + lh;                                                \
    _Pragma("unroll") for (int mi = 0; mi < MIC; ++mi) {                      \
      int r = wm * (MIC * 32) + mi * 32 + lr;                                 \
      af[mi][c] = *(const short8*)&As[d][MH][r * 64 + ((c8 ^ (r & 7)) << 3)]; \
    } }
#define RD_B(dst, NH)                                                         \
  _Pragma("unroll") for (int c = 0; c < 4; ++c) {                             \
    const int c8 = c * 2 + lh;                                                \
    int r = wn * 32 + lr;                                                     \
    dst[c] = *(const short8*)&Bs[d][NH][r * 64 + ((c8 ^ (r & 7)) << 3)];      \
  }
#define MM(MH, NH, bfx)                                                       \
  __builtin_amdgcn_s_setprio(1);                                              \
  _Pragma("unroll") for (int c = 0; c < 4; ++c)                               \
    _Pragma("unroll") for (int mi = 0; mi < MIC; ++mi)                        \
      acc[MH][NH][mi] = MFMA32(af[mi][c], bfx[c], acc[MH][NH][mi]);           \
  __builtin_amdgcn_s_setprio(0);
#define BAR_IN                                                                \
  __builtin_amdgcn_sched_barrier(0);                                          \
  __builtin_amdgcn_s_barrier();                                               \
  asm volatile("s_waitcnt lgkmcnt(0)" ::: "memory");                          \
  __builtin_amdgcn_sched_barrier(0);
#define BAR_OUT                                                               \
  __builtin_amdgcn_sched_barrier(0);                                          \
  __builtin_amdgcn_s_barrier();

  const int NT = K >> 6;
  // prologue: stage tile 0 in first-use order (A0, B0 oldest)
  STAGE_A(0, 0, 0); STAGE_B(0, 0, 0); STAGE_B(0, 1, 0); STAGE_A(0, 1, 0);
  if constexpr (MIC == 2) { VMC(4); } else { VMC(3); }
  __builtin_amdgcn_s_barrier();

  short8 af[MIC][4], bf0[4], bf1[4];

  for (int t = 0; t < NT; ++t) {
    const int d = t & 1;
    const bool pre = (t + 1 < NT);
    // ---- phase 1: q(0,0)
    RD_A(0); RD_B(bf0, 0);
    if (pre) STAGE_A(d ^ 1, 0, t + 1);
    BAR_IN;
    MM(0, 0, bf0);
    if (pre) { if constexpr (MIC == 2) { VMC(4); } else { VMC(2); } }
    else     { if constexpr (MIC == 2) { VMC(2); } else { VMC(1); } }
    BAR_OUT;
    // ---- phase 2: q(0,1)
    RD_B(bf1, 1);
    if (pre) STAGE_B(d ^ 1, 0, t + 1);
    BAR_IN;
    MM(0, 1, bf1);
    if (pre) { if constexpr (MIC == 2) { VMC(4); } else { VMC(3); } }
    else     { VMC(0); }
    BAR_OUT;
    // ---- phase 3: q(1,0)
    RD_A(1);
    if (pre) STAGE_B(d ^ 1, 1, t + 1);
    BAR_IN;
    MM(1, 0, bf0);
    asm volatile("" ::: "memory");
    BAR_OUT;
    // ---- phase 4: q(1,1)
    if (pre) STAGE_A(d ^ 1, 1, t + 1);
    BAR_IN;
    MM(1, 1, bf1);
    if (pre) { if constexpr (MIC == 2) { VMC(4); } else { VMC(3); } }
    else     { asm volatile("" ::: "memory"); }
    BAR_OUT;
  }
#undef STAGE_A
#undef STAGE_B
#undef RD_A
#undef RD_B
#undef MM
#undef BAR_IN
#undef BAR_OUT

#pragma unroll
  for (int mh = 0; mh < 2; ++mh)
#pragma unroll
    for (int nh = 0; nh < 2; ++nh)
#pragma unroll
      for (int mi = 0; mi < MIC; ++mi) {
        size_t n = n0 + nh * 128 + wn * 32 + lr;
#pragma unroll
        for (int reg = 0; reg < 16; ++reg) {
          size_t m = m0 + mh * (MIC * 64) + wm * (MIC * 32) + mi * 32 +
                     (reg & 3) + 8 * (reg >> 2) + 4 * lh;
          float v = acc[mh][nh][mi][reg];
          if (MODE == 0) {
            Cb[m * (size_t)N + n] = f2b(v);
          } else if (MODE == 1) {
            Cf[m * (size_t)N + n] = v + R[m * (size_t)N + n];
          } else if (MODE == 2) {
            Cb[m * (size_t)N + n] = f2b(v / (1.0f + __expf(-v)));   // silu
          } else {  // MODE 3: in-place H = G * acc (thread-exclusive elements)
            float g = b2f(Cb[m * (size_t)N + n]);
            Cb[m * (size_t)N + n] = f2b(v * g);
          }
        }
      }
}

// ---------------------------------------------------------------------------
// Flash attention v5 (causal), S^T formulation, q-tile 128, fused q-subtiles.
// Unchanged from round 5 (passed; both q-subtiles share each K/V LDS read).
// ---------------------------------------------------------------------------
__global__ __launch_bounds__(256, 2) void attn_k(
    const u16* __restrict__ qh, const u16* __restrict__ kh,
    const u16* __restrict__ vt, u16* __restrict__ aout) {
  __shared__ __align__(16) u16 Ks[128 * 64];
  __shared__ __align__(16) u16 Vs[64 * 128];
  __shared__ __align__(16) u16 Ps[128 * 136];
  const int tid = threadIdx.x;
  const int l = tid & 63, w = tid >> 6;
  const int q = l & 15, lq = l >> 4;
  const int q0 = (int)(gridDim.x - 1 - blockIdx.x) * 128;  // heavy blocks first
  const int bh = blockIdx.y;
  const size_t base = (size_t)bh * (2048 * 64);
  const int nt = (q0 >> 7) + 1;

  int qcol[2] = {q0 + w * 16 + q, q0 + 64 + w * 16 + q};
  short8 bq[2][2];
#pragma unroll
  for (int sub = 0; sub < 2; ++sub)
#pragma unroll
    for (int kk = 0; kk < 2; ++kk)
      bq[sub][kk] = *(const short8*)(qh + base + (size_t)qcol[sub] * 64 + kk * 32 + lq * 8);

  f32x4 o[2][4] = {};
  float mI[2] = {-1e30f, -1e30f}, lI[2] = {0.0f, 0.0f};
  u16* pr0 = &Ps[(w * 16 + q) * 136];
  u16* pr1 = &Ps[(64 + w * 16 + q) * 136];

  for (int it = 0; it < nt; ++it) {
    const int kv0 = it << 7;
    if (it) __syncthreads();  // WAR: all waves done with previous tile
#pragma unroll
    for (int t = 0; t < 4; ++t) {
      int p = t * 256 + tid;
      int r = p >> 3, cs = p & 7;
      async16(kh + base + (size_t)(kv0 + r) * 64 + ((cs ^ (r & 7)) << 3), &Ks[p * 8]);
    }
#pragma unroll
    for (int t = 0; t < 4; ++t) {
      int p = t * 256 + tid;
      int r = p >> 4, cs = p & 15;
      async16(vt + base + (size_t)r * 2048 + kv0 + ((cs ^ (r & 15)) << 3), &Vs[p * 8]);
    }
    __syncthreads();
    const bool last = (it == nt - 1);

    // S^T = K · Q^T for BOTH subtiles: one ak read feeds two MFMAs.
    f32x4 s[2][8] = {};
#pragma unroll
    for (int kk = 0; kk < 2; ++kk) {
#pragma unroll
      for (int mt = 0; mt < 8; ++mt) {
        int row = mt * 16 + q;
        short8 ak = *(const short8*)&Ks[row * 64 + (((kk * 4 + lq) ^ (q & 7)) << 3)];
        s[0][mt] = MFMA16(ak, bq[0][kk], s[0][mt]);
        s[1][mt] = MFMA16(ak, bq[1][kk], s[1][mt]);
      }
    }
    if (last) {  // causal mask
#pragma unroll
      for (int sub = 0; sub < 2; ++sub)
#pragma unroll
        for (int mt = 0; mt < 8; ++mt)
#pragma unroll
          for (int r = 0; r < 4; ++r)
            if (kv0 + mt * 16 + lq * 4 + r > qcol[sub]) s[sub][mt][r] = -1e30f;
    }
    // online softmax per subtile, exp2 domain (Q prescaled in rope_k)
#pragma unroll
    for (int sub = 0; sub < 2; ++sub) {
      float mx = -1e30f;
#pragma unroll
      for (int mt = 0; mt < 8; ++mt)
#pragma unroll
        for (int r = 0; r < 4; ++r) mx = fmaxf(mx, s[sub][mt][r]);
      mx = fmaxf(mx, __shfl_xor(mx, 16, 64));
      mx = fmaxf(mx, __shfl_xor(mx, 32, 64));
      const float mn = fmaxf(mI[sub], mx);
      const float al = exp2f(mI[sub] - mn);
      mI[sub] = mn;
      float rs = 0.0f;
#pragma unroll
      for (int mt = 0; mt < 8; ++mt)
#pragma unroll
        for (int r = 0; r < 4; ++r) {
          float p = exp2f(s[sub][mt][r] - mn);
          s[sub][mt][r] = p;
          rs += p;
        }
      rs += __shfl_xor(rs, 16, 64);
      rs += __shfl_xor(rs, 32, 64);
      lI[sub] = lI[sub] * al + rs;
#pragma unroll
      for (int mt = 0; mt < 4; ++mt)
#pragma unroll
        for (int r = 0; r < 4; ++r) o[sub][mt][r] *= al;
      u16* pr = sub ? pr1 : pr0;
#pragma unroll
      for (int mt = 0; mt < 8; ++mt) {
        uint2 pd;
        pd.x = pkbf(s[sub][mt][0], s[sub][mt][1]);
        pd.y = pkbf(s[sub][mt][2], s[sub][mt][3]);
        *(uint2*)&pr[mt * 16 + lq * 4] = pd;
      }
    }
    // O^T += V^T · P^T for BOTH subtiles: one av read feeds two MFMAs.
#pragma unroll
    for (int kk = 0; kk < 4; ++kk) {
      short8 bp0 = *(const short8*)&pr0[kk * 32 + lq * 8];
      short8 bp1 = *(const short8*)&pr1[kk * 32 + lq * 8];
#pragma unroll
      for (int mt = 0; mt < 4; ++mt) {
        int row = mt * 16 + q;
        short8 av = *(const short8*)&Vs[row * 128 + (((kk * 4 + lq) ^ (row & 15)) << 3)];
        o[0][mt] = MFMA16(av, bp0, o[0][mt]);
        o[1][mt] = MFMA16(av, bp1, o[1][mt]);
      }
    }
  }
  const int b = bh >> 4, h = bh & 15;
#pragma unroll
  for (int sub = 0; sub < 2; ++sub) {
    const float inv = 1.0f / lI[sub];
#pragma unroll
    for (int mt = 0; mt < 4; ++mt) {
      uint2 pd;
      pd.x = pkbf(o[sub][mt][0] * inv, o[sub][mt][1] * inv);
      pd.y = pkbf(o[sub][mt][2] * inv, o[sub][mt][3] * inv);
      *(uint2*)&aout[((size_t)(b * 2048 + qcol[sub])) * 1024 + h * 64 + mt * 16 + lq * 4] = pd;
    }
  }
}

// ---------------------------------------------------------------------------
// Elementwise helpers (unchanged)
// ---------------------------------------------------------------------------
__global__ __launch_bounds__(256) void rmsnorm_k(
    const float* __restrict__ x, const float* __restrict__ w, u16* __restrict__ out) {
  const int row = blockIdx.x;
  const int tid = threadIdx.x;
  const float4 v = ((const float4*)(x + (size_t)row * 1024))[tid];
  float ss = v.x * v.x + v.y * v.y + v.z * v.z + v.w * v.w;
#pragma unroll
  for (int d = 1; d < 64; d <<= 1) ss += __shfl_xor(ss, d, 64);
  __shared__ float red[4];
  if ((tid & 63) == 0) red[tid >> 6] = ss;
  __syncthreads();
  const float sc = rsqrtf((red[0] + red[1] + red[2] + red[3]) * (1.0f / 1024.0f) + 1e-5f);
  const float4 wv = ((const float4*)w)[tid];
  u16* o = out + (size_t)row * 1024 + tid * 4;
  o[0] = f2b(v.x * sc * wv.x);
  o[1] = f2b(v.y * sc * wv.y);
  o[2] = f2b(v.z * sc * wv.z);
  o[3] = f2b(v.w * sc * wv.w);
}

// RoPE for q AND k from fused QKV [8192][3072] -> QH/KH [b][h][s][64].
__global__ __launch_bounds__(256) void rope_k(
    const u16* __restrict__ qkv, u16* __restrict__ qh, u16* __restrict__ kh,
    const int* __restrict__ pos) {
  int idx = blockIdx.x * 256 + threadIdx.x;  // 8192 rows * 256 groups
  int grp = idx & 255;
  int row = idx >> 8;
  int which = grp >> 7;  // 0=q, 1=k
  int p = grp & 127;
  int s = row & 2047, b = row >> 11;
  int h = p >> 3, gi = p & 7;
  const u16* src = qkv + (size_t)row * 3072 + which * 1024 + h * 64 + gi * 8;
  uint4 in = *(const uint4*)src;
  const u16* e = (const u16*)&in;
  const float fp = (float)pos[s];
  const float scale = which ? 1.0f : 0.18033688011112042f;  // 0.125*log2(e)
  uint4 outv;
  unsigned* ov = (unsigned*)&outv;
#pragma unroll
  for (int j = 0; j < 4; ++j) {
    int i = gi * 4 + j;  // pair index 0..31
    float xe = b2f(e[2 * j]), xo = b2f(e[2 * j + 1]);
    float inv = exp2f(-(float)(2 * i) * (13.287712379549449f / 64.0f));
    float ang = fp * inv;
    float sn, cs;
    __sincosf(ang, &sn, &cs);
    ov[j] = pkbf((xe * cs - xo * sn) * scale, (xe * sn + xo * cs) * scale);
  }
  u16* dst = (which ? kh : qh) + (((size_t)(b * 16 + h)) * 2048 + s) * 64 + gi * 8;
  *(uint4*)dst = outv;
}

// v (cols 2048..3071 of QKV) -> vT [b][h][d][s], 64x64 LDS tile transpose
__global__ __launch_bounds__(256) void transv_k(
    const u16* __restrict__ qkv, u16* __restrict__ vt) {
  __shared__ u16 t[64][65];
  const int bh = blockIdx.y, s0 = blockIdx.x * 64;
  const int b = bh >> 4, h = bh & 15;
  const int tid = threadIdx.x;
#pragma unroll
  for (int i = 0; i < 16; ++i) {
    int e = i * 256 + tid;
    int sl = e >> 6, d = e & 63;
    t[sl][d] = qkv[((size_t)(b * 2048 + s0 + sl)) * 3072 + 2048 + h * 64 + d];
  }
  __syncthreads();
#pragma unroll
  for (int i = 0; i < 16; ++i) {
    int e = i * 256 + tid;
    int d = e >> 6, sl = e & 63;
    vt[((size_t)(bh * 64 + d)) * 2048 + s0 + sl] = t[sl][d];
  }
}

// All 7 weight tensors fp32->bf16 in one launch.
__global__ __launch_bounds__(256) void cvt_all(
    const float* __restrict__ qp, const float* __restrict__ kp,
    const float* __restrict__ vp, const float* __restrict__ op,
    const float* __restrict__ w1, const float* __restrict__ w3,
    const float* __restrict__ w2,
    u16* __restrict__ WQKV, u16* __restrict__ WO,
    u16* __restrict__ W1, u16* __restrict__ W3, u16* __restrict__ W2) {
  int i = blockIdx.x * 256 + threadIdx.x;  // [0, 4194304)
  const float* src;
  u16* dst;
  int off;
  if (i < 1048576) {
    int seg = i >> 18, within = i & 262143;
    src = (seg == 0) ? qp : (seg == 1) ? kp : (seg == 2) ? vp : op;
    dst = (seg == 3) ? WO : WQKV + (size_t)seg * 1048576;
    off = within;
  } else {
    int j = i - 1048576;
    int seg = j >> 20;
    off = j & 1048575;
    src = (seg == 0) ? w1 : (seg == 1) ? w3 : w2;
    dst = (seg == 0) ? W1 : (seg == 1) ? W3 : W2;
  }
  float4 v = ((const float4*)src)[off];
  u16* o = dst + (size_t)off * 4;
  o[0] = f2b(v.x); o[1] = f2b(v.y); o[2] = f2b(v.z); o[3] = f2b(v.w);
}

// ---------------------------------------------------------------------------
extern "C" void kernel_launch(void* const* d_in, const int* in_sizes, int n_in,
                              void* d_out, int out_size, void* d_ws, size_t ws_size,
                              hipStream_t stream) {
  const float* x   = (const float*)d_in[0];
  const int*   pos = (const int*)d_in[1];
  const float* qp  = (const float*)d_in[2];
  const float* kp  = (const float*)d_in[3];
  const float* vp  = (const float*)d_in[4];
  const float* op  = (const float*)d_in[5];
  const float* w1  = (const float*)d_in[6];
  const float* w2  = (const float*)d_in[7];   // dict order: w2 before w3
  const float* w3  = (const float*)d_in[8];
  const float* ln1 = (const float*)d_in[9];
  const float* ln2 = (const float*)d_in[10];
  float* out = (float*)d_out;
  char* ws = (char*)d_ws;
  const size_t MB = 1024 * 1024;

  u16* WQKV = (u16*)(ws + 0 * MB);    // [3072][1024] stacked q,k,v  (6 MB)
  u16* WO   = (u16*)(ws + 6 * MB);    // 2 MB
  u16* W1   = (u16*)(ws + 8 * MB);    // 8 MB
  u16* W3   = (u16*)(ws + 16 * MB);   // 8 MB
  u16* W2   = (u16*)(ws + 24 * MB);   // 8 MB
  u16* XLN  = (u16*)(ws + 32 * MB);   // 16 MB (dead after QKV gemm)
  u16* QKV  = (u16*)(ws + 48 * MB);   // [8192][3072] 48 MB (48..96)
  u16* QH   = (u16*)(ws + 96 * MB);   // 16 MB
  u16* KH   = (u16*)(ws + 112 * MB);  // 16 MB
  u16* VT   = (u16*)(ws + 128 * MB);  // 16 MB (high-water 144 MB)
  u16* ATT  = (u16*)(ws + 48 * MB);   // reuses QKV (dead after rope/transv)
  u16* XLN2 = (u16*)(ws + 32 * MB);   // reuses dead XLN
  u16* GH   = (u16*)(ws + 48 * MB);   // 64 MB (48..112) over dead ATT/QKV/QH
  (void)in_sizes; (void)n_in; (void)out_size; (void)ws_size;

  cvt_all<<<16384, 256, 0, stream>>>(qp, kp, vp, op, w1, w3, w2,
                                     WQKV, WO, W1, W3, W2);
  rmsnorm_k<<<8192, 256, 0, stream>>>(x, ln1, XLN);
  gemm8<0, 1><<<dim3(12, 64), 512, 0, stream>>>(XLN, WQKV, QKV, nullptr, nullptr, 8192, 3072, 1024);
  rope_k<<<8192, 256, 0, stream>>>(QKV, QH, KH, pos);
  transv_k<<<dim3(32, 64), 256, 0, stream>>>(QKV, VT);
  attn_k<<<dim3(16, 64), 256, 0, stream>>>(QH, KH, VT, ATT);
  gemm8<1, 1><<<dim3(4, 64), 512, 0, stream>>>(ATT, WO, nullptr, out, x, 8192, 1024, 1024);
  rmsnorm_k<<<8192, 256, 0, stream>>>(out, ln2, XLN2);
  // FFN: U = silu(XLN2 @ W1^T) -> GH ; GH *= XLN2 @ W3^T ; out += GH @ W2^T
  gemm8<2, 2><<<dim3(16, 32), 512, 0, stream>>>(XLN2, W1, GH, nullptr, nullptr, 8192, 4096, 1024);
  gemm8<3, 2><<<dim3(16, 32), 512, 0, stream>>>(XLN2, W3, GH, nullptr, nullptr, 8192, 4096, 1024);
  gemm8<1, 1><<<dim3(4, 64), 512, 0, stream>>>(GH, W2, nullptr, out, out, 8192, 1024, 4096);
}

// Round 4
// 576.232 us; speedup vs baseline: 1.3122x; 1.2828x over previous
//
#include <hip/hip_runtime.h>
#include <hip/hip_bf16.h>

// TransformerBlock on MI355X (gfx950) — round 8.
// GEMMs: reverted to the R1-proven 128²/4-wave structure (877 TF measured in
// this harness; two 8-phase ports measured SLOWER — 500/560 TF — barrier
// granularity per MFMA was worse than the compiler's own schedule).
// Attn v6: (a) paired q-tiles (block x runs tiles {15-x, x}) -> uniform 17
// tile-units/block, 512 blocks = exactly 2/CU, no straggler tail (was the
// 10.5% OccupancyPercent); (b) K/V staging split with counted vmcnt + raw
// barriers so prefetch stays in flight under softmax/PV (was vmcnt(0) drain
// per tile). QK/softmax/PV math identical to the R5-passed kernel.
// B=4 S=2048 D=1024 H=16 DK=64 DFF=4096. fp32 in/out, bf16 tensor-core compute.

typedef unsigned short u16;
typedef __attribute__((ext_vector_type(8))) short short8;    // 8 bf16 (MFMA A/B frag)
typedef __attribute__((ext_vector_type(4))) float f32x4;     // 16x16 C/D frag
typedef __attribute__((ext_vector_type(16))) float f32x16;   // 32x32 C/D frag

#define MFMA16(a, b, c) __builtin_amdgcn_mfma_f32_16x16x32_bf16(a, b, c, 0, 0, 0)
#define MFMA32(a, b, c) __builtin_amdgcn_mfma_f32_32x32x16_bf16(a, b, c, 0, 0, 0)
#define VMC(N) asm volatile("s_waitcnt vmcnt(" #N ")" ::: "memory")

__device__ __forceinline__ u16 f2b(float f) {
  union { float f; unsigned u; } x; x.f = f;
  unsigned r = x.u + 0x7FFFu + ((x.u >> 16) & 1u);   // RNE
  return (u16)(r >> 16);
}
__device__ __forceinline__ float b2f(u16 h) {
  union { unsigned u; float f; } x; x.u = ((unsigned)h) << 16;
  return x.f;
}
__device__ __forceinline__ unsigned pkbf(float a, float b) {
  __hip_bfloat162 h = __float22bfloat162_rn(make_float2(a, b));
  union { __hip_bfloat162 h; unsigned u; } cv; cv.h = h;
  return cv.u;
}
// async global->LDS, 16B per lane; LDS dest = wave-uniform base + lane*16.
__device__ __forceinline__ void async16(const void* g, void* l) {
  __builtin_amdgcn_global_load_lds(
      (const __attribute__((address_space(1))) void*)g,
      (__attribute__((address_space(3))) void*)l, 16, 0, 0);
}

// ---------------------------------------------------------------------------
// GEMM (bt-form): C[m,n] = sum_k A[m,k]*B[n,k] — R1-proven structure.
// ---------------------------------------------------------------------------
template <int MODE>
__global__ __launch_bounds__(256, 2) void gemm_bt(
    const u16* __restrict__ A, const u16* __restrict__ B,
    u16* __restrict__ Cb, float* __restrict__ Cf, const float* __restrict__ R,
    int M, int N, int K) {
  __shared__ __align__(16) u16 As[128 * 64];
  __shared__ __align__(16) u16 Bs[128 * 64];
  const int tid = threadIdx.x;
  const int l = tid & 63, w = tid >> 6;
  const int wr = w & 1, wc = w >> 1;
  const int lr = l & 31, lh = l >> 5;
  const size_t m0 = (size_t)blockIdx.y * 128, n0 = (size_t)blockIdx.x * 128;
  f32x16 acc[2][2] = {};
  for (int k0 = 0; k0 < K; k0 += 64) {
#pragma unroll
    for (int t = 0; t < 4; ++t) {
      int c = t * 256 + tid;
      int r = c >> 3;
      int gc = ((c & 7) ^ (r & 7)) << 3;
      async16(A + (m0 + r) * (size_t)K + k0 + gc, &As[c * 8]);
    }
#pragma unroll
    for (int t = 0; t < 4; ++t) {
      int c = t * 256 + tid;
      int r = c >> 3;
      int gc = ((c & 7) ^ (r & 7)) << 3;
      async16(B + (n0 + r) * (size_t)K + k0 + gc, &Bs[c * 8]);
    }
    __syncthreads();
#pragma unroll
    for (int c = 0; c < 4; ++c) {
      const int c8 = c * 2 + lh;
      short8 af[2], bfr[2];
#pragma unroll
      for (int mi = 0; mi < 2; ++mi) {
        int r = wr * 64 + mi * 32 + lr;
        af[mi] = *(const short8*)&As[r * 64 + ((c8 ^ (r & 7)) << 3)];
      }
#pragma unroll
      for (int ni = 0; ni < 2; ++ni) {
        int r = wc * 64 + ni * 32 + lr;
        bfr[ni] = *(const short8*)&Bs[r * 64 + ((c8 ^ (r & 7)) << 3)];
      }
#pragma unroll
      for (int mi = 0; mi < 2; ++mi)
#pragma unroll
        for (int ni = 0; ni < 2; ++ni)
          acc[mi][ni] = MFMA32(af[mi], bfr[ni], acc[mi][ni]);
    }
    __syncthreads();
  }
#pragma unroll
  for (int mi = 0; mi < 2; ++mi)
#pragma unroll
    for (int ni = 0; ni < 2; ++ni) {
      size_t n = n0 + wc * 64 + ni * 32 + lr;
#pragma unroll
      for (int reg = 0; reg < 16; ++reg) {
        size_t m = m0 + wr * 64 + mi * 32 + (reg & 3) + 8 * (reg >> 2) + 4 * lh;
        float v = acc[mi][ni][reg];
        if (MODE == 0)
          Cb[m * (size_t)N + n] = f2b(v);
        else
          Cf[m * (size_t)N + n] = v + R[m * (size_t)N + n];
      }
    }
}

// ---------------------------------------------------------------------------
// Fused SwiGLU GEMM — R1-proven.
// ---------------------------------------------------------------------------
__global__ __launch_bounds__(256, 2) void ffn_gemm(
    const u16* __restrict__ A, const u16* __restrict__ B1,
    const u16* __restrict__ B3, u16* __restrict__ Hout, int M, int N, int K) {
  __shared__ __align__(16) u16 As[128 * 64];
  __shared__ __align__(16) u16 B1s[128 * 64];
  __shared__ __align__(16) u16 B3s[128 * 64];
  const int tid = threadIdx.x;
  const int l = tid & 63, w = tid >> 6;
  const int wr = w & 1, wc = w >> 1;
  const int lr = l & 31, lh = l >> 5;
  const size_t m0 = (size_t)blockIdx.y * 128, n0 = (size_t)blockIdx.x * 128;
  f32x16 a1[2][2] = {}, a3[2][2] = {};
  for (int k0 = 0; k0 < K; k0 += 64) {
#pragma unroll
    for (int t = 0; t < 4; ++t) {
      int c = t * 256 + tid;
      int r = c >> 3;
      int gc = ((c & 7) ^ (r & 7)) << 3;
      async16(A + (m0 + r) * (size_t)K + k0 + gc, &As[c * 8]);
      async16(B1 + (n0 + r) * (size_t)K + k0 + gc, &B1s[c * 8]);
      async16(B3 + (n0 + r) * (size_t)K + k0 + gc, &B3s[c * 8]);
    }
    __syncthreads();
#pragma unroll
    for (int c = 0; c < 4; ++c) {
      const int c8 = c * 2 + lh;
      short8 af[2], b1f[2], b3f[2];
#pragma unroll
      for (int mi = 0; mi < 2; ++mi) {
        int r = wr * 64 + mi * 32 + lr;
        af[mi] = *(const short8*)&As[r * 64 + ((c8 ^ (r & 7)) << 3)];
      }
#pragma unroll
      for (int ni = 0; ni < 2; ++ni) {
        int r = wc * 64 + ni * 32 + lr;
        b1f[ni] = *(const short8*)&B1s[r * 64 + ((c8 ^ (r & 7)) << 3)];
        b3f[ni] = *(const short8*)&B3s[r * 64 + ((c8 ^ (r & 7)) << 3)];
      }
#pragma unroll
      for (int mi = 0; mi < 2; ++mi)
#pragma unroll
        for (int ni = 0; ni < 2; ++ni) {
          a1[mi][ni] = MFMA32(af[mi], b1f[ni], a1[mi][ni]);
          a3[mi][ni] = MFMA32(af[mi], b3f[ni], a3[mi][ni]);
        }
    }
    __syncthreads();
  }
#pragma unroll
  for (int mi = 0; mi < 2; ++mi)
#pragma unroll
    for (int ni = 0; ni < 2; ++ni) {
      size_t n = n0 + wc * 64 + ni * 32 + lr;
#pragma unroll
      for (int reg = 0; reg < 16; ++reg) {
        size_t m = m0 + wr * 64 + mi * 32 + (reg & 3) + 8 * (reg >> 2) + 4 * lh;
        float u = a1[mi][ni][reg];
        float g = u / (1.0f + __expf(-u));  // silu
        Hout[m * (size_t)N + n] = f2b(g * a3[mi][ni][reg]);
      }
    }
}

// ---------------------------------------------------------------------------
// Flash attention v6 (causal), S^T formulation, fused q-subtiles.
// Grid (8, B*H): block x runs q-tiles {15-x, x} (heavy then light) -> every
// block does exactly 17 tile-units; 512 blocks = 2/CU, no tail.
// Staging split: V(it) issued at tile entry (hides under QK+softmax),
// K(it+1) issued after the post-QK barrier (hides under softmax+PV),
// counted vmcnt so prefetch never drains. 3 raw barriers/tile.
// LDS: Ks 16KB + Vs 16KB + Ps 34KB = 66KB -> 2 blocks/CU.
// ---------------------------------------------------------------------------
__global__ __launch_bounds__(256, 2) void attn_k(
    const u16* __restrict__ qh, const u16* __restrict__ kh,
    const u16* __restrict__ vt, u16* __restrict__ aout) {
  __shared__ __align__(16) u16 Ks[128 * 64];
  __shared__ __align__(16) u16 Vs[64 * 128];
  __shared__ __align__(16) u16 Ps[128 * 136];
  const int tid = threadIdx.x;
  const int l = tid & 63, w = tid >> 6;
  const int q = l & 15, lq = l >> 4;
  const int bh = blockIdx.y;
  const size_t base = (size_t)bh * (2048 * 64);
  const int b = bh >> 4, h = bh & 15;

#define STAGE_K(kvt)                                                          \
  { _Pragma("unroll") for (int t = 0; t < 4; ++t) {                           \
      int p = t * 256 + tid;                                                  \
      int r = p >> 3, cs = p & 7;                                             \
      async16(kh + base + (size_t)((kvt) * 128 + r) * 64 + ((cs ^ (r & 7)) << 3), \
              &Ks[p * 8]); } }
#define STAGE_V(kvt)                                                          \
  { _Pragma("unroll") for (int t = 0; t < 4; ++t) {                           \
      int p = t * 256 + tid;                                                  \
      int r = p >> 4, cs = p & 15;                                            \
      async16(vt + base + (size_t)r * 2048 + (kvt) * 128 + ((cs ^ (r & 15)) << 3), \
              &Vs[p * 8]); } }
#define BARRIER                                                               \
  __builtin_amdgcn_sched_barrier(0);                                          \
  __builtin_amdgcn_s_barrier();                                               \
  __builtin_amdgcn_sched_barrier(0)

#pragma unroll 1
  for (int pass = 0; pass < 2; ++pass) {
    const int qt = pass ? (int)blockIdx.x : 15 - (int)blockIdx.x;
    const int q0 = qt << 7;
    const int nt = qt + 1;
    const int qcol[2] = {q0 + w * 16 + q, q0 + 64 + w * 16 + q};
    short8 bq[2][2];
#pragma unroll
    for (int sub = 0; sub < 2; ++sub)
#pragma unroll
      for (int kk = 0; kk < 2; ++kk)
        bq[sub][kk] = *(const short8*)(qh + base + (size_t)qcol[sub] * 64 + kk * 32 + lq * 8);

    f32x4 o[2][4] = {};
    float mI[2] = {-1e30f, -1e30f}, lI[2] = {0.0f, 0.0f};
    u16* pr0 = &Ps[(w * 16 + q) * 136];
    u16* pr1 = &Ps[(64 + w * 16 + q) * 136];

    BARRIER;            // WAR vs previous pass's Ks/Vs reads (pass 0: harmless)
    STAGE_K(0);
    STAGE_V(0);

#pragma unroll 1
    for (int it = 0; it < nt; ++it) {
      // K(it) landed (its 4 loads are the oldest; V(it)/others may stay in flight)
      if (it == 0) { VMC(4); } else { VMC(0); }
      BARRIER;          // K(it) visible to all waves; prev PV done -> Vs reusable
      if (it) STAGE_V(it);

      // S^T = K · Q^T for BOTH subtiles: one ak read feeds two MFMAs.
      f32x4 s[2][8] = {};
#pragma unroll
      for (int kk = 0; kk < 2; ++kk) {
#pragma unroll
        for (int mt = 0; mt < 8; ++mt) {
          int row = mt * 16 + q;
          short8 ak = *(const short8*)&Ks[row * 64 + (((kk * 4 + lq) ^ (q & 7)) << 3)];
          s[0][mt] = MFMA16(ak, bq[0][kk], s[0][mt]);
          s[1][mt] = MFMA16(ak, bq[1][kk], s[1][mt]);
        }
      }
      BARRIER;          // all waves done reading Ks -> safe to restage K
      if (it + 1 < nt) STAGE_K(it + 1);

      const bool last = (it == nt - 1);
      if (last) {  // causal mask
        const int kv0 = it << 7;
#pragma unroll
        for (int sub = 0; sub < 2; ++sub)
#pragma unroll
          for (int mt = 0; mt < 8; ++mt)
#pragma unroll
            for (int r = 0; r < 4; ++r)
              if (kv0 + mt * 16 + lq * 4 + r > qcol[sub]) s[sub][mt][r] = -1e30f;
      }
      // online softmax per subtile, exp2 domain (Q prescaled in rope_k)
#pragma unroll
      for (int sub = 0; sub < 2; ++sub) {
        float mx = -1e30f;
#pragma unroll
        for (int mt = 0; mt < 8; ++mt)
#pragma unroll
          for (int r = 0; r < 4; ++r) mx = fmaxf(mx, s[sub][mt][r]);
        mx = fmaxf(mx, __shfl_xor(mx, 16, 64));
        mx = fmaxf(mx, __shfl_xor(mx, 32, 64));
        const float mn = fmaxf(mI[sub], mx);
        const float al = exp2f(mI[sub] - mn);
        mI[sub] = mn;
        float rs = 0.0f;
#pragma unroll
        for (int mt = 0; mt < 8; ++mt)
#pragma unroll
          for (int r = 0; r < 4; ++r) {
            float p = exp2f(s[sub][mt][r] - mn);
            s[sub][mt][r] = p;
            rs += p;
          }
        rs += __shfl_xor(rs, 16, 64);
        rs += __shfl_xor(rs, 32, 64);
        lI[sub] = lI[sub] * al + rs;
#pragma unroll
        for (int mt = 0; mt < 4; ++mt)
#pragma unroll
          for (int r = 0; r < 4; ++r) o[sub][mt][r] *= al;
        u16* pr = sub ? pr1 : pr0;
#pragma unroll
        for (int mt = 0; mt < 8; ++mt) {
          uint2 pd;
          pd.x = pkbf(s[sub][mt][0], s[sub][mt][1]);
          pd.y = pkbf(s[sub][mt][2], s[sub][mt][3]);
          *(uint2*)&pr[mt * 16 + lq * 4] = pd;
        }
      }
      // V(it) landed (K(it+1), if issued, stays in flight)
      if (it + 1 < nt) { VMC(4); } else { VMC(0); }
      BARRIER;          // V(it) visible to all waves
      // O^T += V^T · P^T for BOTH subtiles: one av read feeds two MFMAs.
#pragma unroll
      for (int kk = 0; kk < 4; ++kk) {
        short8 bp0 = *(const short8*)&pr0[kk * 32 + lq * 8];
        short8 bp1 = *(const short8*)&pr1[kk * 32 + lq * 8];
#pragma unroll
        for (int mt = 0; mt < 4; ++mt) {
          int row = mt * 16 + q;
          short8 av = *(const short8*)&Vs[row * 128 + (((kk * 4 + lq) ^ (row & 15)) << 3)];
          o[0][mt] = MFMA16(av, bp0, o[0][mt]);
          o[1][mt] = MFMA16(av, bp1, o[1][mt]);
        }
      }
    }
#pragma unroll
    for (int sub = 0; sub < 2; ++sub) {
      const float inv = 1.0f / lI[sub];
#pragma unroll
      for (int mt = 0; mt < 4; ++mt) {
        uint2 pd;
        pd.x = pkbf(o[sub][mt][0] * inv, o[sub][mt][1] * inv);
        pd.y = pkbf(o[sub][mt][2] * inv, o[sub][mt][3] * inv);
        *(uint2*)&aout[((size_t)(b * 2048 + qcol[sub])) * 1024 + h * 64 + mt * 16 + lq * 4] = pd;
      }
    }
  }
#undef STAGE_K
#undef STAGE_V
#undef BARRIER
}

// ---------------------------------------------------------------------------
// Elementwise helpers (unchanged)
// ---------------------------------------------------------------------------
__global__ __launch_bounds__(256) void rmsnorm_k(
    const float* __restrict__ x, const float* __restrict__ w, u16* __restrict__ out) {
  const int row = blockIdx.x;
  const int tid = threadIdx.x;
  const float4 v = ((const float4*)(x + (size_t)row * 1024))[tid];
  float ss = v.x * v.x + v.y * v.y + v.z * v.z + v.w * v.w;
#pragma unroll
  for (int d = 1; d < 64; d <<= 1) ss += __shfl_xor(ss, d, 64);
  __shared__ float red[4];
  if ((tid & 63) == 0) red[tid >> 6] = ss;
  __syncthreads();
  const float sc = rsqrtf((red[0] + red[1] + red[2] + red[3]) * (1.0f / 1024.0f) + 1e-5f);
  const float4 wv = ((const float4*)w)[tid];
  u16* o = out + (size_t)row * 1024 + tid * 4;
  o[0] = f2b(v.x * sc * wv.x);
  o[1] = f2b(v.y * sc * wv.y);
  o[2] = f2b(v.z * sc * wv.z);
  o[3] = f2b(v.w * sc * wv.w);
}

// RoPE for q AND k from fused QKV [8192][3072] -> QH/KH [b][h][s][64].
__global__ __launch_bounds__(256) void rope_k(
    const u16* __restrict__ qkv, u16* __restrict__ qh, u16* __restrict__ kh,
    const int* __restrict__ pos) {
  int idx = blockIdx.x * 256 + threadIdx.x;  // 8192 rows * 256 groups
  int grp = idx & 255;
  int row = idx >> 8;
  int which = grp >> 7;  // 0=q, 1=k
  int p = grp & 127;
  int s = row & 2047, b = row >> 11;
  int h = p >> 3, gi = p & 7;
  const u16* src = qkv + (size_t)row * 3072 + which * 1024 + h * 64 + gi * 8;
  uint4 in = *(const uint4*)src;
  const u16* e = (const u16*)&in;
  const float fp = (float)pos[s];
  const float scale = which ? 1.0f : 0.18033688011112042f;  // 0.125*log2(e)
  uint4 outv;
  unsigned* ov = (unsigned*)&outv;
#pragma unroll
  for (int j = 0; j < 4; ++j) {
    int i = gi * 4 + j;  // pair index 0..31
    float xe = b2f(e[2 * j]), xo = b2f(e[2 * j + 1]);
    float inv = exp2f(-(float)(2 * i) * (13.287712379549449f / 64.0f));
    float ang = fp * inv;
    float sn, cs;
    __sincosf(ang, &sn, &cs);
    ov[j] = pkbf((xe * cs - xo * sn) * scale, (xe * sn + xo * cs) * scale);
  }
  u16* dst = (which ? kh : qh) + (((size_t)(b * 16 + h)) * 2048 + s) * 64 + gi * 8;
  *(uint4*)dst = outv;
}

// v (cols 2048..3071 of QKV) -> vT [b][h][d][s], 64x64 LDS tile transpose
__global__ __launch_bounds__(256) void transv_k(
    const u16* __restrict__ qkv, u16* __restrict__ vt) {
  __shared__ u16 t[64][65];
  const int bh = blockIdx.y, s0 = blockIdx.x * 64;
  const int b = bh >> 4, h = bh & 15;
  const int tid = threadIdx.x;
#pragma unroll
  for (int i = 0; i < 16; ++i) {
    int e = i * 256 + tid;
    int sl = e >> 6, d = e & 63;
    t[sl][d] = qkv[((size_t)(b * 2048 + s0 + sl)) * 3072 + 2048 + h * 64 + d];
  }
  __syncthreads();
#pragma unroll
  for (int i = 0; i < 16; ++i) {
    int e = i * 256 + tid;
    int d = e >> 6, sl = e & 63;
    vt[((size_t)(bh * 64 + d)) * 2048 + s0 + sl] = t[sl][d];
  }
}

// All 7 weight tensors fp32->bf16 in one launch.
__global__ __launch_bounds__(256) void cvt_all(
    const float* __restrict__ qp, const float* __restrict__ kp,
    const float* __restrict__ vp, const float* __restrict__ op,
    const float* __restrict__ w1, const float* __restrict__ w3,
    const float* __restrict__ w2,
    u16* __restrict__ WQKV, u16* __restrict__ WO,
    u16* __restrict__ W1, u16* __restrict__ W3, u16* __restrict__ W2) {
  int i = blockIdx.x * 256 + threadIdx.x;  // [0, 4194304)
  const float* src;
  u16* dst;
  int off;
  if (i < 1048576) {
    int seg = i >> 18, within = i & 262143;
    src = (seg == 0) ? qp : (seg == 1) ? kp : (seg == 2) ? vp : op;
    dst = (seg == 3) ? WO : WQKV + (size_t)seg * 1048576;
    off = within;
  } else {
    int j = i - 1048576;
    int seg = j >> 20;
    off = j & 1048575;
    src = (seg == 0) ? w1 : (seg == 1) ? w3 : w2;
    dst = (seg == 0) ? W1 : (seg == 1) ? W3 : W2;
  }
  float4 v = ((const float4*)src)[off];
  u16* o = dst + (size_t)off * 4;
  o[0] = f2b(v.x); o[1] = f2b(v.y); o[2] = f2b(v.z); o[3] = f2b(v.w);
}

// ---------------------------------------------------------------------------
extern "C" void kernel_launch(void* const* d_in, const int* in_sizes, int n_in,
                              void* d_out, int out_size, void* d_ws, size_t ws_size,
                              hipStream_t stream) {
  const float* x   = (const float*)d_in[0];
  const int*   pos = (const int*)d_in[1];
  const float* qp  = (const float*)d_in[2];
  const float* kp  = (const float*)d_in[3];
  const float* vp  = (const float*)d_in[4];
  const float* op  = (const float*)d_in[5];
  const float* w1  = (const float*)d_in[6];
  const float* w2  = (const float*)d_in[7];   // dict order: w2 before w3
  const float* w3  = (const float*)d_in[8];
  const float* ln1 = (const float*)d_in[9];
  const float* ln2 = (const float*)d_in[10];
  float* out = (float*)d_out;
  char* ws = (char*)d_ws;
  const size_t MB = 1024 * 1024;

  u16* WQKV = (u16*)(ws + 0 * MB);    // [3072][1024] stacked q,k,v  (6 MB)
  u16* WO   = (u16*)(ws + 6 * MB);
  u16* W1   = (u16*)(ws + 8 * MB);
  u16* W3   = (u16*)(ws + 16 * MB);
  u16* W2   = (u16*)(ws + 24 * MB);
  u16* XLN  = (u16*)(ws + 32 * MB);
  u16* QKV  = (u16*)(ws + 48 * MB);   // [8192][3072]  (48..96 MB)
  u16* QH   = (u16*)(ws + 96 * MB);
  u16* KH   = (u16*)(ws + 112 * MB);
  u16* VT   = (u16*)(ws + 128 * MB);
  u16* ATT  = (u16*)(ws + 48 * MB);   // reuses QKV
  u16* XLN2 = (u16*)(ws + 64 * MB);
  u16* Hbuf = (u16*)(ws + 80 * MB);   // 64 MB (VT dead by then)
  (void)in_sizes; (void)n_in; (void)out_size; (void)ws_size;

  cvt_all<<<16384, 256, 0, stream>>>(qp, kp, vp, op, w1, w3, w2,
                                     WQKV, WO, W1, W3, W2);
  rmsnorm_k<<<8192, 256, 0, stream>>>(x, ln1, XLN);
  gemm_bt<0><<<dim3(24, 64), 256, 0, stream>>>(XLN, WQKV, QKV, nullptr, nullptr, 8192, 3072, 1024);
  rope_k<<<8192, 256, 0, stream>>>(QKV, QH, KH, pos);
  transv_k<<<dim3(32, 64), 256, 0, stream>>>(QKV, VT);
  attn_k<<<dim3(8, 64), 256, 0, stream>>>(QH, KH, VT, ATT);
  gemm_bt<1><<<dim3(8, 64), 256, 0, stream>>>(ATT, WO, nullptr, out, x, 8192, 1024, 1024);
  rmsnorm_k<<<8192, 256, 0, stream>>>(out, ln2, XLN2);
  ffn_gemm<<<dim3(32, 64), 256, 0, stream>>>(XLN2, W1, W3, Hbuf, 8192, 4096, 1024);
  gemm_bt<1><<<dim3(8, 64), 256, 0, stream>>>(Hbuf, W2, nullptr, out, out, 8192, 1024, 4096);
}

// Round 5
// 573.952 us; speedup vs baseline: 1.3175x; 1.0040x over previous
//
#include <hip/hip_runtime.h>
#include <hip/hip_bf16.h>

// TransformerBlock on MI355X (gfx950) — round 9: faithful m201 8-phase port
// for ffn_gemm only. R6 failed coarse (32 MFMA/barrier), R7 failed fine
// (4 MFMA32/barrier, vmcnt every phase). ffn8p matches the template: 8
// MFMA32 (=16 MFMA16-equiv, 262K FLOP) per barrier-pair, reads 12/4/8/0
// with register-persistent fragments, ONE vmcnt(4) per K-tile (counted,
// never 0 until drain), ~1.5-tile prefetch lookahead, setprio around MFMA.
// Grid 32x32 = 1024 blocks = exactly 4 full CU-rounds. Everything else is
// the R4-proven kernel (576us) + uint2-packed stores in rmsnorm/cvt_all.
// B=4 S=2048 D=1024 H=16 DK=64 DFF=4096. fp32 in/out, bf16 tensor-core.

typedef unsigned short u16;
typedef __attribute__((ext_vector_type(8))) short short8;    // 8 bf16 (MFMA A/B frag)
typedef __attribute__((ext_vector_type(4))) float f32x4;     // 16x16 C/D frag
typedef __attribute__((ext_vector_type(16))) float f32x16;   // 32x32 C/D frag

#define MFMA16(a, b, c) __builtin_amdgcn_mfma_f32_16x16x32_bf16(a, b, c, 0, 0, 0)
#define MFMA32(a, b, c) __builtin_amdgcn_mfma_f32_32x32x16_bf16(a, b, c, 0, 0, 0)
#define VMC(N) asm volatile("s_waitcnt vmcnt(" #N ")" ::: "memory")

__device__ __forceinline__ u16 f2b(float f) {
  union { float f; unsigned u; } x; x.f = f;
  unsigned r = x.u + 0x7FFFu + ((x.u >> 16) & 1u);   // RNE
  return (u16)(r >> 16);
}
__device__ __forceinline__ float b2f(u16 h) {
  union { unsigned u; float f; } x; x.u = ((unsigned)h) << 16;
  return x.f;
}
__device__ __forceinline__ unsigned pkbf(float a, float b) {
  __hip_bfloat162 h = __float22bfloat162_rn(make_float2(a, b));
  union { __hip_bfloat162 h; unsigned u; } cv; cv.h = h;
  return cv.u;
}
// async global->LDS, 16B per lane; LDS dest = wave-uniform base + lane*16.
__device__ __forceinline__ void async16(const void* g, void* l) {
  __builtin_amdgcn_global_load_lds(
      (const __attribute__((address_space(1))) void*)g,
      (__attribute__((address_space(3))) void*)l, 16, 0, 0);
}

// ---------------------------------------------------------------------------
// GEMM (bt-form): C[m,n] = sum_k A[m,k]*B[n,k] — R1-proven structure.
// ---------------------------------------------------------------------------
template <int MODE>
__global__ __launch_bounds__(256, 2) void gemm_bt(
    const u16* __restrict__ A, const u16* __restrict__ B,
    u16* __restrict__ Cb, float* __restrict__ Cf, const float* __restrict__ R,
    int M, int N, int K) {
  __shared__ __align__(16) u16 As[128 * 64];
  __shared__ __align__(16) u16 Bs[128 * 64];
  const int tid = threadIdx.x;
  const int l = tid & 63, w = tid >> 6;
  const int wr = w & 1, wc = w >> 1;
  const int lr = l & 31, lh = l >> 5;
  const size_t m0 = (size_t)blockIdx.y * 128, n0 = (size_t)blockIdx.x * 128;
  f32x16 acc[2][2] = {};
  for (int k0 = 0; k0 < K; k0 += 64) {
#pragma unroll
    for (int t = 0; t < 4; ++t) {
      int c = t * 256 + tid;
      int r = c >> 3;
      int gc = ((c & 7) ^ (r & 7)) << 3;
      async16(A + (m0 + r) * (size_t)K + k0 + gc, &As[c * 8]);
    }
#pragma unroll
    for (int t = 0; t < 4; ++t) {
      int c = t * 256 + tid;
      int r = c >> 3;
      int gc = ((c & 7) ^ (r & 7)) << 3;
      async16(B + (n0 + r) * (size_t)K + k0 + gc, &Bs[c * 8]);
    }
    __syncthreads();
#pragma unroll
    for (int c = 0; c < 4; ++c) {
      const int c8 = c * 2 + lh;
      short8 af[2], bfr[2];
#pragma unroll
      for (int mi = 0; mi < 2; ++mi) {
        int r = wr * 64 + mi * 32 + lr;
        af[mi] = *(const short8*)&As[r * 64 + ((c8 ^ (r & 7)) << 3)];
      }
#pragma unroll
      for (int ni = 0; ni < 2; ++ni) {
        int r = wc * 64 + ni * 32 + lr;
        bfr[ni] = *(const short8*)&Bs[r * 64 + ((c8 ^ (r & 7)) << 3)];
      }
#pragma unroll
      for (int mi = 0; mi < 2; ++mi)
#pragma unroll
        for (int ni = 0; ni < 2; ++ni)
          acc[mi][ni] = MFMA32(af[mi], bfr[ni], acc[mi][ni]);
    }
    __syncthreads();
  }
#pragma unroll
  for (int mi = 0; mi < 2; ++mi)
#pragma unroll
    for (int ni = 0; ni < 2; ++ni) {
      size_t n = n0 + wc * 64 + ni * 32 + lr;
#pragma unroll
      for (int reg = 0; reg < 16; ++reg) {
        size_t m = m0 + wr * 64 + mi * 32 + (reg & 3) + 8 * (reg >> 2) + 4 * lh;
        float v = acc[mi][ni][reg];
        if (MODE == 0)
          Cb[m * (size_t)N + n] = f2b(v);
        else
          Cf[m * (size_t)N + n] = v + R[m * (size_t)N + n];
      }
    }
}

// ---------------------------------------------------------------------------
// ffn8p: fused SwiGLU GEMM, m201-style 8-phase schedule.
// Tile BM=256 x BN=128, BK=64. 8 waves (wm 2 x wn 4); per-wave out 128x32
// for BOTH U and V3 (acc = 8 f32x16 = 128 VGPR).
// LDS 128KB: As[2dbuf][2mhalf][128x64] + B1s[2][128x64] + B3s[2][128x64].
// Per K-tile, 4 phases x {reads; stage 1 unit; barrier; lgkmcnt(0); 8 MFMA32;
// barrier}. Reads 12/4/8/0 (frags persist in regs). Stage order:
// p1 A0[t+1], p2 A1[t+1], p3 B1[t+2], p4 B3[t+2]; ONE vmcnt(4) at tile end
// retires all of tile t+1 (2 units stay in flight). Region liveness:
// A-halves free after p3, B1 after p1, B3 after p2 — all stage slots legal.
// ---------------------------------------------------------------------------
__global__ __launch_bounds__(512, 2) void ffn8p(
    const u16* __restrict__ A, const u16* __restrict__ B1,
    const u16* __restrict__ B3, u16* __restrict__ Hout,
    int M, int N, int K) {
  __shared__ __align__(16) u16 As[2][2][128 * 64];
  __shared__ __align__(16) u16 B1s[2][128 * 64];
  __shared__ __align__(16) u16 B3s[2][128 * 64];
  const int tid = threadIdx.x;
  const int l = tid & 63, w = tid >> 6;
  const int wm = w >> 2, wn = w & 3;
  const int lr = l & 31, lh = l >> 5;
  const size_t m0 = (size_t)blockIdx.y * 256, n0 = (size_t)blockIdx.x * 128;
  f32x16 aU[2][2] = {}, aV[2][2] = {};

#define STG_A(dd, hh, kt)                                                    \
  { const size_t kofs = (size_t)(kt) * 64;                                   \
    _Pragma("unroll") for (int j = 0; j < 2; ++j) {                          \
      int p = j * 512 + tid;                                                 \
      int r = p >> 3, c8 = p & 7;                                            \
      async16(A + (m0 + (hh) * 128 + r) * (size_t)K + kofs                   \
                  + (((c8) ^ (r & 7)) << 3),                                 \
              &As[dd][hh][p * 8]); } }
#define STG_B(dd, kt, Bp, Bls)                                               \
  { const size_t kofs = (size_t)(kt) * 64;                                   \
    _Pragma("unroll") for (int j = 0; j < 2; ++j) {                          \
      int p = j * 512 + tid;                                                 \
      int r = p >> 3, c8 = p & 7;                                            \
      async16(Bp + (n0 + r) * (size_t)K + kofs + (((c8) ^ (r & 7)) << 3),    \
              &Bls[dd][p * 8]); } }
#define RD_A(QM)                                                             \
  _Pragma("unroll") for (int c = 0; c < 4; ++c) {                            \
    const int c8 = c * 2 + lh;                                               \
    _Pragma("unroll") for (int mi = 0; mi < 2; ++mi) {                       \
      int rr = (QM) * 64 + mi * 32 + lr;                                     \
      af[mi][c] = *(const short8*)&As[d][wm][rr * 64 + (((c8) ^ (rr & 7)) << 3)]; \
    } }
#define RD_B(dst, Bls)                                                       \
  _Pragma("unroll") for (int c = 0; c < 4; ++c) {                            \
    const int c8 = c * 2 + lh;                                               \
    const int rb = wn * 32 + lr;                                             \
    dst[c] = *(const short8*)&Bls[d][rb * 64 + (((c8) ^ (rb & 7)) << 3)];    \
  }
#define MMX(accq, bfx)                                                       \
  __builtin_amdgcn_s_setprio(1);                                             \
  _Pragma("unroll") for (int c = 0; c < 4; ++c)                              \
    _Pragma("unroll") for (int mi = 0; mi < 2; ++mi)                         \
      accq[mi] = MFMA32(af[mi][c], bfx[c], accq[mi]);                        \
  __builtin_amdgcn_s_setprio(0);
#define SB0 __builtin_amdgcn_sched_barrier(0)
#define BARX { SB0; __builtin_amdgcn_s_barrier(); SB0; }
#define LGKM0 { asm volatile("s_waitcnt lgkmcnt(0)" ::: "memory"); SB0; }

  const int NT = K >> 6;
  // prologue: tile 0 fully + tile 1's B units (consumption-order oldest first)
  STG_A(0, 0, 0); STG_A(0, 1, 0);
  STG_B(0, 0, B1, B1s); STG_B(0, 0, B3, B3s);
  STG_B(1, 1, B1, B1s); STG_B(1, 1, B3, B3s);
  VMC(4);   // tile 0's 4 units landed; tile 1's B1,B3 in flight
  SB0;
  __builtin_amdgcn_s_barrier();

  short8 af[2][4], b1f[4], b3f[4];

  for (int t = 0; t < NT; ++t) {
    const int d = t & 1;
    // ---- phase 1: U, quadrant qm0  (reads 12)
    RD_A(0); RD_B(b1f, B1s);
    if (t + 1 < NT) STG_A(d ^ 1, 0, t + 1);
    BARX; LGKM0;
    MMX(aU[0], b1f);
    BARX;
    // ---- phase 2: V3, quadrant qm0  (reads 4; af qm0 reused)
    RD_B(b3f, B3s);
    if (t + 1 < NT) STG_A(d ^ 1, 1, t + 1);
    BARX; LGKM0;
    MMX(aV[0], b3f);
    BARX;
    // ---- phase 3: U, quadrant qm1  (reads 8; b1f reused)
    RD_A(1);
    if (t + 2 < NT) STG_B(d, t + 2, B1, B1s);
    BARX; LGKM0;
    MMX(aU[1], b1f);
    BARX;
    // ---- phase 4: V3, quadrant qm1  (reads 0; af qm1 + b3f reused)
    if (t + 2 < NT) STG_B(d, t + 2, B3, B3s);
    BARX; LGKM0;
    MMX(aV[1], b3f);
    if (t + 2 < NT) { VMC(4); }        // tile t+1 complete; 2 units in flight
    else if (t + 1 < NT) { VMC(0); }   // drain for last tile
    SB0;
    BARX;
  }
#undef STG_A
#undef STG_B
#undef RD_A
#undef RD_B
#undef MMX

  // epilogue: silu(U) * V3, bf16 store
#pragma unroll
  for (int qm = 0; qm < 2; ++qm)
#pragma unroll
    for (int mi = 0; mi < 2; ++mi) {
      size_t n = n0 + wn * 32 + lr;
#pragma unroll
      for (int reg = 0; reg < 16; ++reg) {
        size_t m = m0 + wm * 128 + qm * 64 + mi * 32 + (reg & 3) + 8 * (reg >> 2) + 4 * lh;
        float u = aU[qm][mi][reg];
        float g = u / (1.0f + __expf(-u));  // silu
        Hout[m * (size_t)N + n] = f2b(g * aV[qm][mi][reg]);
      }
    }
}

// ---------------------------------------------------------------------------
// Flash attention v6 (causal) — unchanged from R4 (proven, ~92us).
// ---------------------------------------------------------------------------
__global__ __launch_bounds__(256, 2) void attn_k(
    const u16* __restrict__ qh, const u16* __restrict__ kh,
    const u16* __restrict__ vt, u16* __restrict__ aout) {
  __shared__ __align__(16) u16 Ks[128 * 64];
  __shared__ __align__(16) u16 Vs[64 * 128];
  __shared__ __align__(16) u16 Ps[128 * 136];
  const int tid = threadIdx.x;
  const int l = tid & 63, w = tid >> 6;
  const int q = l & 15, lq = l >> 4;
  const int bh = blockIdx.y;
  const size_t base = (size_t)bh * (2048 * 64);
  const int b = bh >> 4, h = bh & 15;

#define STAGE_K(kvt)                                                          \
  { _Pragma("unroll") for (int t = 0; t < 4; ++t) {                           \
      int p = t * 256 + tid;                                                  \
      int r = p >> 3, cs = p & 7;                                             \
      async16(kh + base + (size_t)((kvt) * 128 + r) * 64 + ((cs ^ (r & 7)) << 3), \
              &Ks[p * 8]); } }
#define STAGE_V(kvt)                                                          \
  { _Pragma("unroll") for (int t = 0; t < 4; ++t) {                           \
      int p = t * 256 + tid;                                                  \
      int r = p >> 4, cs = p & 15;                                            \
      async16(vt + base + (size_t)r * 2048 + (kvt) * 128 + ((cs ^ (r & 15)) << 3), \
              &Vs[p * 8]); } }
#define BARRIER                                                               \
  __builtin_amdgcn_sched_barrier(0);                                          \
  __builtin_amdgcn_s_barrier();                                               \
  __builtin_amdgcn_sched_barrier(0)

#pragma unroll 1
  for (int pass = 0; pass < 2; ++pass) {
    const int qt = pass ? (int)blockIdx.x : 15 - (int)blockIdx.x;
    const int q0 = qt << 7;
    const int nt = qt + 1;
    const int qcol[2] = {q0 + w * 16 + q, q0 + 64 + w * 16 + q};
    short8 bq[2][2];
#pragma unroll
    for (int sub = 0; sub < 2; ++sub)
#pragma unroll
      for (int kk = 0; kk < 2; ++kk)
        bq[sub][kk] = *(const short8*)(qh + base + (size_t)qcol[sub] * 64 + kk * 32 + lq * 8);

    f32x4 o[2][4] = {};
    float mI[2] = {-1e30f, -1e30f}, lI[2] = {0.0f, 0.0f};
    u16* pr0 = &Ps[(w * 16 + q) * 136];
    u16* pr1 = &Ps[(64 + w * 16 + q) * 136];

    BARRIER;            // WAR vs previous pass's Ks/Vs reads (pass 0: harmless)
    STAGE_K(0);
    STAGE_V(0);

#pragma unroll 1
    for (int it = 0; it < nt; ++it) {
      if (it == 0) { VMC(4); } else { VMC(0); }
      BARRIER;          // K(it) visible; prev PV done -> Vs reusable
      if (it) STAGE_V(it);

      f32x4 s[2][8] = {};
#pragma unroll
      for (int kk = 0; kk < 2; ++kk) {
#pragma unroll
        for (int mt = 0; mt < 8; ++mt) {
          int row = mt * 16 + q;
          short8 ak = *(const short8*)&Ks[row * 64 + (((kk * 4 + lq) ^ (q & 7)) << 3)];
          s[0][mt] = MFMA16(ak, bq[0][kk], s[0][mt]);
          s[1][mt] = MFMA16(ak, bq[1][kk], s[1][mt]);
        }
      }
      BARRIER;          // all waves done reading Ks -> safe to restage K
      if (it + 1 < nt) STAGE_K(it + 1);

      const bool last = (it == nt - 1);
      if (last) {  // causal mask
        const int kv0 = it << 7;
#pragma unroll
        for (int sub = 0; sub < 2; ++sub)
#pragma unroll
          for (int mt = 0; mt < 8; ++mt)
#pragma unroll
            for (int r = 0; r < 4; ++r)
              if (kv0 + mt * 16 + lq * 4 + r > qcol[sub]) s[sub][mt][r] = -1e30f;
      }
#pragma unroll
      for (int sub = 0; sub < 2; ++sub) {
        float mx = -1e30f;
#pragma unroll
        for (int mt = 0; mt < 8; ++mt)
#pragma unroll
          for (int r = 0; r < 4; ++r) mx = fmaxf(mx, s[sub][mt][r]);
        mx = fmaxf(mx, __shfl_xor(mx, 16, 64));
        mx = fmaxf(mx, __shfl_xor(mx, 32, 64));
        const float mn = fmaxf(mI[sub], mx);
        const float al = exp2f(mI[sub] - mn);
        mI[sub] = mn;
        float rs = 0.0f;
#pragma unroll
        for (int mt = 0; mt < 8; ++mt)
#pragma unroll
          for (int r = 0; r < 4; ++r) {
            float p = exp2f(s[sub][mt][r] - mn);
            s[sub][mt][r] = p;
            rs += p;
          }
        rs += __shfl_xor(rs, 16, 64);
        rs += __shfl_xor(rs, 32, 64);
        lI[sub] = lI[sub] * al + rs;
#pragma unroll
        for (int mt = 0; mt < 4; ++mt)
#pragma unroll
          for (int r = 0; r < 4; ++r) o[sub][mt][r] *= al;
        u16* pr = sub ? pr1 : pr0;
#pragma unroll
        for (int mt = 0; mt < 8; ++mt) {
          uint2 pd;
          pd.x = pkbf(s[sub][mt][0], s[sub][mt][1]);
          pd.y = pkbf(s[sub][mt][2], s[sub][mt][3]);
          *(uint2*)&pr[mt * 16 + lq * 4] = pd;
        }
      }
      if (it + 1 < nt) { VMC(4); } else { VMC(0); }
      BARRIER;          // V(it) visible
#pragma unroll
      for (int kk = 0; kk < 4; ++kk) {
        short8 bp0 = *(const short8*)&pr0[kk * 32 + lq * 8];
        short8 bp1 = *(const short8*)&pr1[kk * 32 + lq * 8];
#pragma unroll
        for (int mt = 0; mt < 4; ++mt) {
          int row = mt * 16 + q;
          short8 av = *(const short8*)&Vs[row * 128 + (((kk * 4 + lq) ^ (row & 15)) << 3)];
          o[0][mt] = MFMA16(av, bp0, o[0][mt]);
          o[1][mt] = MFMA16(av, bp1, o[1][mt]);
        }
      }
    }
#pragma unroll
    for (int sub = 0; sub < 2; ++sub) {
      const float inv = 1.0f / lI[sub];
#pragma unroll
      for (int mt = 0; mt < 4; ++mt) {
        uint2 pd;
        pd.x = pkbf(o[sub][mt][0] * inv, o[sub][mt][1] * inv);
        pd.y = pkbf(o[sub][mt][2] * inv, o[sub][mt][3] * inv);
        *(uint2*)&aout[((size_t)(b * 2048 + qcol[sub])) * 1024 + h * 64 + mt * 16 + lq * 4] = pd;
      }
    }
  }
#undef STAGE_K
#undef STAGE_V
#undef BARRIER
}

// ---------------------------------------------------------------------------
// Elementwise helpers (uint2-packed stores this round)
// ---------------------------------------------------------------------------
__global__ __launch_bounds__(256) void rmsnorm_k(
    const float* __restrict__ x, const float* __restrict__ w, u16* __restrict__ out) {
  const int row = blockIdx.x;
  const int tid = threadIdx.x;
  const float4 v = ((const float4*)(x + (size_t)row * 1024))[tid];
  float ss = v.x * v.x + v.y * v.y + v.z * v.z + v.w * v.w;
#pragma unroll
  for (int d = 1; d < 64; d <<= 1) ss += __shfl_xor(ss, d, 64);
  __shared__ float red[4];
  if ((tid & 63) == 0) red[tid >> 6] = ss;
  __syncthreads();
  const float sc = rsqrtf((red[0] + red[1] + red[2] + red[3]) * (1.0f / 1024.0f) + 1e-5f);
  const float4 wv = ((const float4*)w)[tid];
  uint2 pv;
  pv.x = pkbf(v.x * sc * wv.x, v.y * sc * wv.y);
  pv.y = pkbf(v.z * sc * wv.z, v.w * sc * wv.w);
  *(uint2*)(out + (size_t)row * 1024 + tid * 4) = pv;
}

// RoPE for q AND k from fused QKV [8192][3072] -> QH/KH [b][h][s][64].
__global__ __launch_bounds__(256) void rope_k(
    const u16* __restrict__ qkv, u16* __restrict__ qh, u16* __restrict__ kh,
    const int* __restrict__ pos) {
  int idx = blockIdx.x * 256 + threadIdx.x;  // 8192 rows * 256 groups
  int grp = idx & 255;
  int row = idx >> 8;
  int which = grp >> 7;  // 0=q, 1=k
  int p = grp & 127;
  int s = row & 2047, b = row >> 11;
  int h = p >> 3, gi = p & 7;
  const u16* src = qkv + (size_t)row * 3072 + which * 1024 + h * 64 + gi * 8;
  uint4 in = *(const uint4*)src;
  const u16* e = (const u16*)&in;
  const float fp = (float)pos[s];
  const float scale = which ? 1.0f : 0.18033688011112042f;  // 0.125*log2(e)
  uint4 outv;
  unsigned* ov = (unsigned*)&outv;
#pragma unroll
  for (int j = 0; j < 4; ++j) {
    int i = gi * 4 + j;  // pair index 0..31
    float xe = b2f(e[2 * j]), xo = b2f(e[2 * j + 1]);
    float inv = exp2f(-(float)(2 * i) * (13.287712379549449f / 64.0f));
    float ang = fp * inv;
    float sn, cs;
    __sincosf(ang, &sn, &cs);
    ov[j] = pkbf((xe * cs - xo * sn) * scale, (xe * sn + xo * cs) * scale);
  }
  u16* dst = (which ? kh : qh) + (((size_t)(b * 16 + h)) * 2048 + s) * 64 + gi * 8;
  *(uint4*)dst = outv;
}

// v (cols 2048..3071 of QKV) -> vT [b][h][d][s], 64x64 LDS tile transpose
__global__ __launch_bounds__(256) void transv_k(
    const u16* __restrict__ qkv, u16* __restrict__ vt) {
  __shared__ u16 t[64][65];
  const int bh = blockIdx.y, s0 = blockIdx.x * 64;
  const int b = bh >> 4, h = bh & 15;
  const int tid = threadIdx.x;
#pragma unroll
  for (int i = 0; i < 16; ++i) {
    int e = i * 256 + tid;
    int sl = e >> 6, d = e & 63;
    t[sl][d] = qkv[((size_t)(b * 2048 + s0 + sl)) * 3072 + 2048 + h * 64 + d];
  }
  __syncthreads();
#pragma unroll
  for (int i = 0; i < 16; ++i) {
    int e = i * 256 + tid;
    int d = e >> 6, sl = e & 63;
    vt[((size_t)(bh * 64 + d)) * 2048 + s0 + sl] = t[sl][d];
  }
}

// All 7 weight tensors fp32->bf16 in one launch (uint2-packed stores).
__global__ __launch_bounds__(256) void cvt_all(
    const float* __restrict__ qp, const float* __restrict__ kp,
    const float* __restrict__ vp, const float* __restrict__ op,
    const float* __restrict__ w1, const float* __restrict__ w3,
    const float* __restrict__ w2,
    u16* __restrict__ WQKV, u16* __restrict__ WO,
    u16* __restrict__ W1, u16* __restrict__ W3, u16* __restrict__ W2) {
  int i = blockIdx.x * 256 + threadIdx.x;  // [0, 4194304)
  const float* src;
  u16* dst;
  int off;
  if (i < 1048576) {
    int seg = i >> 18, within = i & 262143;
    src = (seg == 0) ? qp : (seg == 1) ? kp : (seg == 2) ? vp : op;
    dst = (seg == 3) ? WO : WQKV + (size_t)seg * 1048576;
    off = within;
  } else {
    int j = i - 1048576;
    int seg = j >> 20;
    off = j & 1048575;
    src = (seg == 0) ? w1 : (seg == 1) ? w3 : w2;
    dst = (seg == 0) ? W1 : (seg == 1) ? W3 : W2;
  }
  float4 v = ((const float4*)src)[off];
  uint2 pv;
  pv.x = pkbf(v.x, v.y);
  pv.y = pkbf(v.z, v.w);
  *(uint2*)(dst + (size_t)off * 4) = pv;
}

// ---------------------------------------------------------------------------
extern "C" void kernel_launch(void* const* d_in, const int* in_sizes, int n_in,
                              void* d_out, int out_size, void* d_ws, size_t ws_size,
                              hipStream_t stream) {
  const float* x   = (const float*)d_in[0];
  const int*   pos = (const int*)d_in[1];
  const float* qp  = (const float*)d_in[2];
  const float* kp  = (const float*)d_in[3];
  const float* vp  = (const float*)d_in[4];
  const float* op  = (const float*)d_in[5];
  const float* w1  = (const float*)d_in[6];
  const float* w2  = (const float*)d_in[7];   // dict order: w2 before w3
  const float* w3  = (const float*)d_in[8];
  const float* ln1 = (const float*)d_in[9];
  const float* ln2 = (const float*)d_in[10];
  float* out = (float*)d_out;
  char* ws = (char*)d_ws;
  const size_t MB = 1024 * 1024;

  u16* WQKV = (u16*)(ws + 0 * MB);    // [3072][1024] stacked q,k,v  (6 MB)
  u16* WO   = (u16*)(ws + 6 * MB);
  u16* W1   = (u16*)(ws + 8 * MB);
  u16* W3   = (u16*)(ws + 16 * MB);
  u16* W2   = (u16*)(ws + 24 * MB);
  u16* XLN  = (u16*)(ws + 32 * MB);
  u16* QKV  = (u16*)(ws + 48 * MB);   // [8192][3072]  (48..96 MB)
  u16* QH   = (u16*)(ws + 96 * MB);
  u16* KH   = (u16*)(ws + 112 * MB);
  u16* VT   = (u16*)(ws + 128 * MB);
  u16* ATT  = (u16*)(ws + 48 * MB);   // reuses QKV
  u16* XLN2 = (u16*)(ws + 64 * MB);
  u16* Hbuf = (u16*)(ws + 80 * MB);   // 64 MB (VT dead by then)
  (void)in_sizes; (void)n_in; (void)out_size; (void)ws_size;

  cvt_all<<<16384, 256, 0, stream>>>(qp, kp, vp, op, w1, w3, w2,
                                     WQKV, WO, W1, W3, W2);
  rmsnorm_k<<<8192, 256, 0, stream>>>(x, ln1, XLN);
  gemm_bt<0><<<dim3(24, 64), 256, 0, stream>>>(XLN, WQKV, QKV, nullptr, nullptr, 8192, 3072, 1024);
  rope_k<<<8192, 256, 0, stream>>>(QKV, QH, KH, pos);
  transv_k<<<dim3(32, 64), 256, 0, stream>>>(QKV, VT);
  attn_k<<<dim3(8, 64), 256, 0, stream>>>(QH, KH, VT, ATT);
  gemm_bt<1><<<dim3(8, 64), 256, 0, stream>>>(ATT, WO, nullptr, out, x, 8192, 1024, 1024);
  rmsnorm_k<<<8192, 256, 0, stream>>>(out, ln2, XLN2);
  ffn8p<<<dim3(32, 32), 512, 0, stream>>>(XLN2, W1, W3, Hbuf, 8192, 4096, 1024);
  gemm_bt<1><<<dim3(8, 64), 256, 0, stream>>>(Hbuf, W2, nullptr, out, out, 8192, 1024, 4096);
}